// Round 1
// baseline (68367.096 us; speedup 1.0000x reference)
//
#include <hip/hip_runtime.h>

#define BN 8
#define NP 2048
#define KK 20
#define EPSV 1e-5f

static __device__ __forceinline__ float leakyf(float v){ return v >= 0.f ? v : 0.2f*v; }
static __device__ __forceinline__ unsigned fenc(float f){
  unsigned u = __float_as_uint(f);
  return (u & 0x80000000u) ? ~u : (u | 0x80000000u);
}
static __device__ __forceinline__ float fdec(unsigned u){
  return __uint_as_float((u & 0x80000000u) ? (u & 0x7FFFFFFFu) : ~u);
}

// ---------------- xx = sum_c x^2 ----------------
__global__ __launch_bounds__(256) void xx_kernel(const float* __restrict__ x, long ldb, int C,
                                                 float* __restrict__ xx){
  int b = blockIdx.y;
  int n = blockIdx.x*256 + threadIdx.x;
  const float* xp = x + (long)b*ldb + n;
  float a = 0.f;
  for(int c=0;c<C;c++){ float v = xp[(long)c*NP]; a += v*v; }
  xx[b*NP + n] = a;
}

// ---------------- knn top-20 (ties -> lower index, matching lax.top_k) ----------------
template<int C>
__global__ __launch_bounds__(256) void knn_kernel(const float* __restrict__ x, long ldb,
                                                  const float* __restrict__ xx,
                                                  int* __restrict__ idxout){
  __shared__ float smemf[12800]; // union: cf[C][64] (<=16KB) | mv 6400 floats + mi 6400 ints
  int b = blockIdx.y;
  int q0 = blockIdx.x*16;
  int t = threadIdx.x;
  int q = t >> 4, s = t & 15;
  int qg = q0 + q;
  const float* xb = x + (long)b*ldb;
  float qf[C];
  #pragma unroll
  for(int c=0;c<C;c++) qf[c] = xb[(long)c*NP + qg];
  float qxx = xx[b*NP + qg];
  float tv[20]; int ti[20];
  #pragma unroll
  for(int r=0;r<20;r++){ tv[r] = -__builtin_inff(); ti[r] = 0x7FFFFFFF; }
  float (*cf)[64] = (float(*)[64])smemf;

  for(int ct=0; ct<NP/64; ct++){
    __syncthreads();
    for(int i=t; i<64*C; i+=256){ int c = i>>6, m = i&63; cf[c][m] = xb[(long)c*NP + ct*64 + m]; }
    __syncthreads();
    #pragma unroll
    for(int j=0;j<4;j++){
      int m = s*4 + j;
      float acc = 0.f;
      #pragma unroll
      for(int c=0;c<C;c++) acc += qf[c]*cf[c][m];
      int gi = ct*64 + m;
      float neg = 2.f*acc - qxx - xx[b*NP + gi];
      if (neg > tv[19] || (neg == tv[19] && gi < ti[19])){
        tv[19] = neg; ti[19] = gi;
        #pragma unroll
        for(int r=19;r>0;r--){
          bool sw = (tv[r] > tv[r-1]) || (tv[r]==tv[r-1] && ti[r] < ti[r-1]);
          if (sw){
            float tf = tv[r]; tv[r]=tv[r-1]; tv[r-1]=tf;
            int  tii = ti[r]; ti[r]=ti[r-1]; ti[r-1]=tii;
          }
        }
      }
    }
  }
  __syncthreads();
  float* mv = smemf;
  int*   mi = (int*)(smemf + 6400);
  #pragma unroll
  for(int r=0;r<20;r++){ mv[(q*16+s)*20 + r] = tv[r]; mi[(q*16+s)*20 + r] = ti[r]; }
  __syncthreads();
  if (t < 16){
    int qq = t;
    int base = qq*320;
    float hv[16]; int hi[16]; int p[16];
    #pragma unroll
    for(int s2=0;s2<16;s2++){ p[s2]=0; hv[s2]=mv[base+s2*20]; hi[s2]=mi[base+s2*20]; }
    int* op = idxout + ((long)b*NP + q0 + qq)*KK;
    for(int r=0;r<KK;r++){
      float bv = hv[0]; int bi = hi[0]; int wsl = 0;
      #pragma unroll
      for(int s2=1;s2<16;s2++){
        bool bt = (hv[s2] > bv) || (hv[s2]==bv && hi[s2] < bi);
        if (bt){ bv = hv[s2]; bi = hi[s2]; wsl = s2; }
      }
      op[r] = bi;
      #pragma unroll
      for(int s2=0;s2<16;s2++){
        if (s2 == wsl){
          p[s2]++;
          if (p[s2] < 20){ hv[s2]=mv[base+s2*20+p[s2]]; hi[s2]=mi[base+s2*20+p[s2]]; }
          else { hv[s2] = -__builtin_inff(); hi[s2] = 0x7FFFFFFF; }
        }
      }
    }
  }
}

// ---------------- edge conv as two small GEMMs: ya = Wa@x, dd = (Wb-Wa)@x, layout (B,N,O) ----------------
template<int CIN, int O>
__global__ __launch_bounds__(256) void pcdual_kernel(const float* __restrict__ x, long ldb,
                                                     const float* __restrict__ W,
                                                     float* __restrict__ ya, float* __restrict__ dd){
  __shared__ float Wt[CIN][O+1];
  constexpr int NLOC = 256/O;
  const int b = blockIdx.y;
  const int n0 = blockIdx.x*NLOC;
  const int t = threadIdx.x;
  const int o = t % O;
  const int n = n0 + t/O;
  const float* xp = x + (long)b*ldb + n;
  float xv[CIN];
  #pragma unroll
  for(int c=0;c<CIN;c++) xv[c] = xp[(long)c*NP];
  for(int i=t;i<CIN*O;i+=256){ int oo=i/CIN, c=i%CIN; Wt[c][oo] = W[(long)oo*2*CIN + c]; }
  __syncthreads();
  float aa = 0.f;
  #pragma unroll
  for(int c=0;c<CIN;c++) aa += Wt[c][o]*xv[c];
  __syncthreads();
  for(int i=t;i<CIN*O;i+=256){ int oo=i/CIN, c=i%CIN; Wt[c][oo] = W[(long)oo*2*CIN + CIN + c]; }
  __syncthreads();
  float ab = 0.f;
  #pragma unroll
  for(int c=0;c<CIN;c++) ab += Wt[c][o]*xv[c];
  long outoff = ((long)b*NP + n)*O + o;
  ya[outoff] = aa;
  dd[outoff] = ab - aa;
}

// ---------------- edge gather: per (b,o,n) max/min over k; per (b,group) sum/sumsq ----------------
template<int O>
__global__ void egather_kernel(const float* __restrict__ ya, const float* __restrict__ dd,
                               const int* __restrict__ idx,
                               float* __restrict__ mx, float* __restrict__ mn,
                               float* __restrict__ stats){
  const int b = blockIdx.y;
  const int n0 = blockIdx.x*8;
  const int o = threadIdx.x;
  constexpr int CPG = O/8;
  float gs = 0.f, gs2 = 0.f;
  const float* yab = ya + (long)b*NP*O;
  for(int p=0;p<8;p++){
    int n = n0 + p;
    float d = dd[((long)b*NP + n)*O + o];
    const int* ip = idx + ((long)b*NP + n)*KK;
    float m = -__builtin_inff(), mm = __builtin_inff(), s = 0.f, s2 = 0.f;
    #pragma unroll
    for(int k=0;k<KK;k++){
      int j = ip[k];
      float v = yab[(long)j*O + o] + d;
      s += v; s2 += v*v;
      m = fmaxf(m, v); mm = fminf(mm, v);
    }
    mx[((long)b*NP + n)*O + o] = m;
    mn[((long)b*NP + n)*O + o] = mm;
    gs += s; gs2 += s2;
  }
  #pragma unroll
  for(int offm=1; offm<CPG; offm<<=1){
    gs  += __shfl_xor(gs,  offm, CPG);
    gs2 += __shfl_xor(gs2, offm, CPG);
  }
  if ((o & (CPG-1)) == 0){
    int g = o / CPG;
    atomicAdd(&stats[(b*8 + g)*2],   gs);
    atomicAdd(&stats[(b*8 + g)*2+1], gs2);
  }
}

// ---------------- edge normalize (+leaky) with (N,O)->(O,N) transpose into feats ----------------
template<int O>
__global__ __launch_bounds__(256) void enorm_kernel(const float* __restrict__ mx, const float* __restrict__ mn,
                                                    const float* __restrict__ stats,
                                                    const float* __restrict__ gw, const float* __restrict__ gb,
                                                    float* __restrict__ feats, int coff){
  __shared__ float lmx[64][65];
  __shared__ float lmn[64][65];
  const int b = blockIdx.z;
  const int o0 = blockIdx.y*64;
  const int n0 = blockIdx.x*64;
  const int t = threadIdx.x;
  for(int r=0;r<16;r++){
    int i = r*4 + t/64, j = t%64;
    long src = ((long)b*NP + n0 + i)*O + o0 + j;
    lmx[i][j] = mx[src];
    lmn[i][j] = mn[src];
  }
  __syncthreads();
  constexpr int CPG = O/8;
  const float inv_cnt = 1.f/((float)CPG*NP*KK);
  for(int r=0;r<16;r++){
    int ol = r*4 + t/64, nl = t%64;
    int og = o0 + ol;
    int g = og / CPG;
    float S  = stats[(b*8+g)*2];
    float S2 = stats[(b*8+g)*2+1];
    float mu = S*inv_cnt;
    float var = S2*inv_cnt - mu*mu;
    float rs = rsqrtf(var + EPSV);
    float w = gw[og], bb = gb[og];
    float sel = (w >= 0.f) ? lmx[nl][ol] : lmn[nl][ol];
    float v = (sel - mu)*rs*w + bb;
    feats[((long)b*256 + coff + og)*NP + n0 + nl] = leakyf(v);
  }
}

// ---------------- generic tiled GEMM y=W@x (+bias/base) with optional GN stats and per-(b,o) max/min ----------------
template<bool WRITE_Y, bool DO_STATS, bool DO_MAXMIN>
__global__ __launch_bounds__(256) void gemm_kernel(
    const float* __restrict__ W, int ldw,
    const float* __restrict__ x, long xldb,
    const float* __restrict__ bias, const float* __restrict__ base,
    int O, int C, int gch,
    float* __restrict__ y, float* __restrict__ stats,
    unsigned* __restrict__ mmax, unsigned* __restrict__ mmin)
{
  __shared__ float Wl[32][68];
  __shared__ float Xl[32][132];
  __shared__ float sred[8];
  __shared__ unsigned smax[64];
  __shared__ unsigned smin[64];
  const int b  = blockIdx.z;
  const int o0 = blockIdx.y*64;
  const int nb = blockIdx.x*128;
  const int t  = threadIdx.x;
  const int og = t & 15, ng = t >> 4;
  const int ol = og*4,  nl = ng*8;
  if (DO_STATS && t < 8) sred[t] = 0.f;
  if (DO_MAXMIN && t < 64){ smax[t] = 0u; smin[t] = 0xFFFFFFFFu; }
  float acc[4][8];
  #pragma unroll
  for(int i=0;i<4;i++)
    #pragma unroll
    for(int j=0;j<8;j++) acc[i][j]=0.f;

  const int so = t>>2, scs = (t&3)*8;
  const int sc = t>>3, sns = (t&7)*16;

  for(int cc=0; cc<C; cc+=32){
    __syncthreads();
    {
      const float* wp = W + (long)(o0+so)*ldw + cc + scs;
      float4 w0 = *(const float4*)wp;
      float4 w1 = *(const float4*)(wp+4);
      Wl[scs+0][so]=w0.x; Wl[scs+1][so]=w0.y; Wl[scs+2][so]=w0.z; Wl[scs+3][so]=w0.w;
      Wl[scs+4][so]=w1.x; Wl[scs+5][so]=w1.y; Wl[scs+6][so]=w1.z; Wl[scs+7][so]=w1.w;
    }
    {
      const float* xp = x + (long)b*xldb + (long)(cc+sc)*NP + nb + sns;
      *(float4*)&Xl[sc][sns+0]  = *(const float4*)(xp+0);
      *(float4*)&Xl[sc][sns+4]  = *(const float4*)(xp+4);
      *(float4*)&Xl[sc][sns+8]  = *(const float4*)(xp+8);
      *(float4*)&Xl[sc][sns+12] = *(const float4*)(xp+12);
    }
    __syncthreads();
    #pragma unroll
    for(int c=0;c<32;c++){
      float w0=Wl[c][ol+0], w1=Wl[c][ol+1], w2=Wl[c][ol+2], w3=Wl[c][ol+3];
      #pragma unroll
      for(int j=0;j<8;j++){
        float xv = Xl[c][nl+j];
        acc[0][j] += w0*xv;
        acc[1][j] += w1*xv;
        acc[2][j] += w2*xv;
        acc[3][j] += w3*xv;
      }
    }
  }
  float bb[4];
  #pragma unroll
  for(int i=0;i<4;i++){
    float v = 0.f;
    if (bias) v += bias[o0+ol+i];
    if (base) v += base[(long)b*O + o0+ol+i];
    bb[i]=v;
  }
  #pragma unroll
  for(int i=0;i<4;i++)
    #pragma unroll
    for(int j=0;j<8;j++) acc[i][j] += bb[i];

  if (WRITE_Y){
    #pragma unroll
    for(int i=0;i<4;i++){
      float* yp = y + ((long)b*O + o0+ol+i)*NP + nb + nl;
      float4 a0 = {acc[i][0],acc[i][1],acc[i][2],acc[i][3]};
      float4 a1 = {acc[i][4],acc[i][5],acc[i][6],acc[i][7]};
      *(float4*)(yp+0) = a0;
      *(float4*)(yp+4) = a1;
    }
  }
  if (DO_STATS){
    float s=0.f, s2=0.f;
    #pragma unroll
    for(int i=0;i<4;i++)
      #pragma unroll
      for(int j=0;j<8;j++){ float v=acc[i][j]; s+=v; s2+=v*v; }
    int gib = ol / gch;
    atomicAdd(&sred[gib*2],   s);
    atomicAdd(&sred[gib*2+1], s2);
  }
  if (DO_MAXMIN){
    #pragma unroll
    for(int i=0;i<4;i++){
      float mv=acc[i][0], mw=acc[i][0];
      #pragma unroll
      for(int j=1;j<8;j++){ mv=fmaxf(mv,acc[i][j]); mw=fminf(mw,acc[i][j]); }
      atomicMax(&smax[ol+i], fenc(mv));
      atomicMin(&smin[ol+i], fenc(mw));
    }
  }
  if (DO_STATS || DO_MAXMIN) __syncthreads();
  if (DO_STATS){
    int ngb = 64/gch;
    if (t < ngb*2){
      int g = o0/gch + (t>>1);
      atomicAdd(&stats[((long)b*(O/gch) + g)*2 + (t&1)], sred[t]);
    }
  }
  if (DO_MAXMIN){
    if (t < 64){
      atomicMax(&mmax[(long)b*O + o0 + t], smax[t]);
      atomicMin(&mmin[(long)b*O + o0 + t], smin[t]);
    }
  }
}

// ---------------- in-place GN+relu ----------------
__global__ __launch_bounds__(256) void normrelu_kernel(float* __restrict__ y,
    const float* __restrict__ stats, const float* __restrict__ gw, const float* __restrict__ gb,
    int O, int gch, float inv_cnt)
{
  long i4 = (long)blockIdx.x*256 + threadIdx.x;
  long i = i4*4;
  int o = (int)((i/NP) % O);
  int b = (int)(i/((long)O*NP));
  int g = o / gch;
  const float* sp = stats + ((long)b*(O/gch)+g)*2;
  float mu = sp[0]*inv_cnt;
  float var = sp[1]*inv_cnt - mu*mu;
  float rs = rsqrtf(var + EPSV);
  float a = rs*gw[o];
  float c2 = gb[o] - mu*a;
  float4* yp = (float4*)y;
  float4 v = yp[i4];
  v.x = fmaxf(v.x*a + c2, 0.f);
  v.y = fmaxf(v.y*a + c2, 0.f);
  v.z = fmaxf(v.z*a + c2, 0.f);
  v.w = fmaxf(v.w*a + c2, 0.f);
  yp[i4] = v;
}

// ---------------- xmax = relu(gn(max/min over n)) ----------------
__global__ void xmax_kernel(const unsigned* __restrict__ mmax, const unsigned* __restrict__ mmin,
                            const float* __restrict__ stats, const float* __restrict__ gw,
                            const float* __restrict__ gb, float* __restrict__ xmax){
  int t = blockIdx.x*256 + threadIdx.x;
  int b = t >> 10, o = t & 1023;
  int g = o >> 5;
  const float* sp = stats + (b*32+g)*2;
  const float inv_cnt = 1.f/(32.f*NP);
  float mu = sp[0]*inv_cnt;
  float var = sp[1]*inv_cnt - mu*mu;
  float rs = rsqrtf(var + EPSV);
  float w = gw[o];
  float sel = (w >= 0.f) ? fdec(mmax[t]) : fdec(mmin[t]);
  float v = (sel - mu)*rs*w + gb[o];
  xmax[t] = fmaxf(v, 0.f);
}

// ---------------- base1[b,o] = bs1[o] + Ws1[:, :1024] @ xmax[b] ----------------
__global__ void base1_kernel(const float* __restrict__ Ws1, const float* __restrict__ bs1,
                             const float* __restrict__ xmax, float* __restrict__ base1){
  int t = blockIdx.x*256 + threadIdx.x;
  int b = t >> 9, o = t & 511;
  float a = bs1[o];
  const float* wp = Ws1 + (long)o*1280;
  const float* xp = xmax + b*1024;
  for(int c=0;c<1024;c++) a += wp[c]*xp[c];
  base1[t] = a;
}

// ---------------- final 50-class conv + log_softmax ----------------
__global__ __launch_bounds__(256) void s4_kernel(const float* __restrict__ h3,
                                                 const float* __restrict__ W,
                                                 const float* __restrict__ bias,
                                                 float* __restrict__ out){
  int b = blockIdx.y;
  int n = blockIdx.x*256 + threadIdx.x;
  float hv[128];
  #pragma unroll
  for(int c=0;c<128;c++) hv[c] = h3[((long)b*128 + c)*NP + n];
  float m = -__builtin_inff(), ssum = 0.f;
  for(int o=0;o<50;o++){
    float a = bias[o];
    const float* wp = W + o*128;
    #pragma unroll
    for(int c=0;c<128;c++) a += wp[c]*hv[c];
    if (a > m){ ssum = ssum*__expf(m - a) + 1.f; m = a; }
    else      { ssum += __expf(a - m); }
  }
  float lse = m + __logf(ssum);
  for(int o=0;o<50;o++){
    float a = bias[o];
    const float* wp = W + o*128;
    #pragma unroll
    for(int c=0;c<128;c++) a += wp[c]*hv[c];
    out[((long)b*50 + o)*NP + n] = a - lse;
  }
}

extern "C" void kernel_launch(void* const* d_in, const int* in_sizes, int n_in,
                              void* d_out, int out_size, void* d_ws, size_t ws_size,
                              hipStream_t stream)
{
  const float* x   = (const float*)d_in[0];
  const float* W1  = (const float*)d_in[1];
  const float* W2  = (const float*)d_in[2];
  const float* W3  = (const float*)d_in[3];
  const float* g1w = (const float*)d_in[4];
  const float* g1b = (const float*)d_in[5];
  const float* g2w = (const float*)d_in[6];
  const float* g2b = (const float*)d_in[7];
  const float* g3w = (const float*)d_in[8];
  const float* g3b = (const float*)d_in[9];
  const float* gfw = (const float*)d_in[10];
  const float* gfb = (const float*)d_in[11];
  const float* gs1w= (const float*)d_in[12];
  const float* gs1b= (const float*)d_in[13];
  const float* gs2w= (const float*)d_in[14];
  const float* gs2b= (const float*)d_in[15];
  const float* gs3w= (const float*)d_in[16];
  const float* gs3b= (const float*)d_in[17];
  const float* Wm  = (const float*)d_in[18];
  const float* bm  = (const float*)d_in[19];
  const float* Ws1 = (const float*)d_in[20];
  const float* bs1 = (const float*)d_in[21];
  const float* Ws2 = (const float*)d_in[22];
  const float* bs2 = (const float*)d_in[23];
  const float* Ws3 = (const float*)d_in[24];
  const float* bs3 = (const float*)d_in[25];
  const float* Ws4 = (const float*)d_in[26];
  const float* bs4 = (const float*)d_in[27];
  float* out = (float*)d_out;

  char* ws = (char*)d_ws;
  size_t off = 0;
  auto alloc = [&](size_t bytes)->char*{
    char* p = ws + off;
    off += (bytes + 255) & ~(size_t)255;
    return p;
  };
  // zeroed region (stats + mmax), then mmin (0xFF)
  char* zbase = alloc(6656 + 32768);
  float* estats1 = (float*)(zbase + 0);
  float* estats2 = (float*)(zbase + 512);
  float* estats3 = (float*)(zbase + 1024);
  float* mstats  = (float*)(zbase + 1536);   // 8*32*2 floats = 2048 B
  float* s1stats = (float*)(zbase + 3584);   // 8*16*2 = 1024 B
  float* s2stats = (float*)(zbase + 4608);   // 1024 B
  float* s3stats = (float*)(zbase + 5632);   // 512 B
  unsigned* mmax = (unsigned*)(zbase + 6656);
  unsigned* mmin = (unsigned*)alloc(32768);
  float* xmaxb = (float*)alloc(8*1024*4);
  float* base1 = (float*)alloc(8*512*4);
  float* feats = (float*)alloc((size_t)BN*256*NP*4);
  int*   idxb  = (int*)  alloc((size_t)BN*NP*KK*4);
  float* xxb   = (float*)alloc((size_t)BN*NP*4);
  float* ya    = (float*)alloc((size_t)BN*NP*128*4);
  float* dd    = (float*)alloc((size_t)BN*NP*128*4);
  float* mx    = (float*)alloc((size_t)BN*NP*128*4);
  float* mn    = (float*)alloc((size_t)BN*NP*128*4);
  float* ybuf1 = (float*)alloc((size_t)BN*512*NP*4);
  float* ybuf2 = (float*)alloc((size_t)BN*256*NP*4);
  float* ybuf3 = (float*)alloc((size_t)BN*128*NP*4);

  hipMemsetAsync(zbase, 0, 6656 + 32768, stream);
  hipMemsetAsync(mmin, 0xFF, 32768, stream);

  dim3 blk256(256);

  // ---- edge block 1 (C=3 -> 64) ----
  xx_kernel<<<dim3(NP/256, BN), blk256, 0, stream>>>(x, (long)3*NP, 3, xxb);
  knn_kernel<3><<<dim3(NP/16, BN), blk256, 0, stream>>>(x, (long)3*NP, xxb, idxb);
  pcdual_kernel<3,64><<<dim3(NP/4, BN), blk256, 0, stream>>>(x, (long)3*NP, W1, ya, dd);
  egather_kernel<64><<<dim3(NP/8, BN), dim3(64), 0, stream>>>(ya, dd, idxb, mx, mn, estats1);
  enorm_kernel<64><<<dim3(NP/64, 1, BN), blk256, 0, stream>>>(mx, mn, estats1, g1w, g1b, feats, 0);

  // ---- edge block 2 (C=64 -> 64) ----
  xx_kernel<<<dim3(NP/256, BN), blk256, 0, stream>>>(feats, (long)256*NP, 64, xxb);
  knn_kernel<64><<<dim3(NP/16, BN), blk256, 0, stream>>>(feats, (long)256*NP, xxb, idxb);
  pcdual_kernel<64,64><<<dim3(NP/4, BN), blk256, 0, stream>>>(feats, (long)256*NP, W2, ya, dd);
  egather_kernel<64><<<dim3(NP/8, BN), dim3(64), 0, stream>>>(ya, dd, idxb, mx, mn, estats2);
  enorm_kernel<64><<<dim3(NP/64, 1, BN), blk256, 0, stream>>>(mx, mn, estats2, g2w, g2b, feats, 64);

  // ---- edge block 3 (C=64 -> 128) ----
  xx_kernel<<<dim3(NP/256, BN), blk256, 0, stream>>>(feats + 64*NP, (long)256*NP, 64, xxb);
  knn_kernel<64><<<dim3(NP/16, BN), blk256, 0, stream>>>(feats + 64*NP, (long)256*NP, xxb, idxb);
  pcdual_kernel<64,128><<<dim3(NP/2, BN), blk256, 0, stream>>>(feats + 64*NP, (long)256*NP, W3, ya, dd);
  egather_kernel<128><<<dim3(NP/8, BN), dim3(128), 0, stream>>>(ya, dd, idxb, mx, mn, estats3);
  enorm_kernel<128><<<dim3(NP/64, 2, BN), blk256, 0, stream>>>(mx, mn, estats3, g3w, g3b, feats, 128);

  // ---- global conv (Wm 1024x256): stats + per-(b,o) max/min only, no y ----
  gemm_kernel<false,true,true><<<dim3(16,16,BN), blk256, 0, stream>>>(
      Wm, 256, feats, (long)256*NP, bm, nullptr, 1024, 256, 32,
      nullptr, mstats, mmax, mmin);
  xmax_kernel<<<dim3(32), blk256, 0, stream>>>(mmax, mmin, mstats, gfw, gfb, xmaxb);
  base1_kernel<<<dim3(16), blk256, 0, stream>>>(Ws1, bs1, xmaxb, base1);

  // ---- seg conv 1 (feats part of Ws1) ----
  gemm_kernel<true,true,false><<<dim3(16,8,BN), blk256, 0, stream>>>(
      Ws1 + 1024, 1280, feats, (long)256*NP, nullptr, base1, 512, 256, 32,
      ybuf1, s1stats, nullptr, nullptr);
  normrelu_kernel<<<dim3((unsigned)((long)BN*512*NP/4/256)), blk256, 0, stream>>>(
      ybuf1, s1stats, gs1w, gs1b, 512, 32, 1.f/(32.f*NP));

  // ---- seg conv 2 ----
  gemm_kernel<true,true,false><<<dim3(16,4,BN), blk256, 0, stream>>>(
      Ws2, 512, ybuf1, (long)512*NP, bs2, nullptr, 256, 512, 16,
      ybuf2, s2stats, nullptr, nullptr);
  normrelu_kernel<<<dim3((unsigned)((long)BN*256*NP/4/256)), blk256, 0, stream>>>(
      ybuf2, s2stats, gs2w, gs2b, 256, 16, 1.f/(16.f*NP));

  // ---- seg conv 3 ----
  gemm_kernel<true,true,false><<<dim3(16,2,BN), blk256, 0, stream>>>(
      Ws3, 256, ybuf2, (long)256*NP, bs3, nullptr, 128, 256, 16,
      ybuf3, s3stats, nullptr, nullptr);
  normrelu_kernel<<<dim3((unsigned)((long)BN*128*NP/4/256)), blk256, 0, stream>>>(
      ybuf3, s3stats, gs3w, gs3b, 128, 16, 1.f/(16.f*NP));

  // ---- final conv + log_softmax ----
  s4_kernel<<<dim3(NP/256, BN), blk256, 0, stream>>>(ybuf3, Ws4, bs4, out);
}

// Round 2
// 1702.802 us; speedup vs baseline: 40.1498x; 40.1498x over previous
//
#include <hip/hip_runtime.h>

#define BN 8
#define NP 2048
#define KK 20
#define EPSV 1e-5f

static __device__ __forceinline__ float leakyf(float v){ return v >= 0.f ? v : 0.2f*v; }
static __device__ __forceinline__ unsigned fenc(float f){
  unsigned u = __float_as_uint(f);
  return (u & 0x80000000u) ? ~u : (u | 0x80000000u);
}
static __device__ __forceinline__ float fdec(unsigned u){
  return __uint_as_float((u & 0x80000000u) ? (u & 0x7FFFFFFFu) : ~u);
}

// ---------------- xx = sum_c x^2 ----------------
__global__ __launch_bounds__(256) void xx_kernel(const float* __restrict__ x, long ldb, int C,
                                                 float* __restrict__ xx){
  int b = blockIdx.y;
  int n = blockIdx.x*256 + threadIdx.x;
  const float* xp = x + (long)b*ldb + n;
  float a = 0.f;
  for(int c=0;c<C;c++){ float v = xp[(long)c*NP]; a += v*v; }
  xx[b*NP + n] = a;
}

// ---------------- knn v2: LDS-tiled distance GEMM + streaming register top-20 ----------------
// block = 128 threads, 32 queries; candidate chunks of 64.
// GEMM map: tq=t>>4 (8), tm=t&15 (16); thread tile 4q x 4m.
// Select map: sq=t>>2 (32), sl=t&3 (4 lanes/query, 16 cands each per chunk).
template<int C>
__global__ __launch_bounds__(128) void knn2_kernel(const float* __restrict__ x, long ldb,
                                                   const float* __restrict__ xx,
                                                   int* __restrict__ idxout){
  constexpr int CBYTES = C*32*4 + C*64*4 + 32*65*4;
  constexpr int MBYTES = 32*4*20*8;
  constexpr int SB = CBYTES > MBYTES ? CBYTES : MBYTES;
  __shared__ __align__(16) char smem[SB];
  float (*qL)[32] = (float(*)[32])smem;
  float (*cL)[64] = (float(*)[64])(smem + C*32*4);
  float (*S)[65]  = (float(*)[65])(smem + C*32*4 + C*64*4);
  float* mv = (float*)smem;
  int*   mi = (int*)(smem + 32*80*4);

  const int b  = blockIdx.y;
  const int q0 = blockIdx.x*32;
  const int t  = threadIdx.x;
  const float* xb  = x + (long)b*ldb;
  const float* xxb = xx + b*NP;

  // stage query features once: qL[c][q]
  for(int i=t; i<C*8; i+=128){
    int c = i>>3, q4 = (i&7)*4;
    *(float4*)&qL[c][q4] = *(const float4*)(xb + (long)c*NP + q0 + q4);
  }

  const int tq = t>>4, tm = t&15;
  const int sq = t>>2, sl = t&3;
  const float qxx = xxb[q0 + sq];

  float tv[20]; int ti[20];
  #pragma unroll
  for(int r=0;r<20;r++){ tv[r] = -__builtin_inff(); ti[r] = 0x7FFFFFFF; }

  for(int ct=0; ct<NP/64; ct++){
    __syncthreads();
    for(int i=t; i<C*16; i+=128){
      int c = i>>4, m4 = (i&15)*4;
      *(float4*)&cL[c][m4] = *(const float4*)(xb + (long)c*NP + ct*64 + m4);
    }
    __syncthreads();
    float acc[4][4];
    #pragma unroll
    for(int i=0;i<4;i++)
      #pragma unroll
      for(int j=0;j<4;j++) acc[i][j] = 0.f;
    #pragma unroll
    for(int c=0;c<C;c++){
      float4 qv = *(const float4*)&qL[c][tq*4];
      float4 cv = *(const float4*)&cL[c][tm*4];
      acc[0][0] += qv.x*cv.x; acc[0][1] += qv.x*cv.y; acc[0][2] += qv.x*cv.z; acc[0][3] += qv.x*cv.w;
      acc[1][0] += qv.y*cv.x; acc[1][1] += qv.y*cv.y; acc[1][2] += qv.y*cv.z; acc[1][3] += qv.y*cv.w;
      acc[2][0] += qv.z*cv.x; acc[2][1] += qv.z*cv.y; acc[2][2] += qv.z*cv.z; acc[2][3] += qv.z*cv.w;
      acc[3][0] += qv.w*cv.x; acc[3][1] += qv.w*cv.y; acc[3][2] += qv.w*cv.z; acc[3][3] += qv.w*cv.w;
    }
    #pragma unroll
    for(int i=0;i<4;i++)
      #pragma unroll
      for(int j=0;j<4;j++) S[tq*4+i][tm*4+j] = acc[i][j];
    __syncthreads();
    // streaming selection: each lane scans its 16 candidates in increasing index order
    for(int j=0;j<16;j++){
      int m  = sl*16 + j;
      int gi = ct*64 + m;
      float neg = 2.f*S[sq][m] - qxx - xxb[gi];
      if (neg > tv[19]){
        tv[19] = neg; ti[19] = gi;
        #pragma unroll
        for(int r=19;r>0;r--){
          bool sw = tv[r] > tv[r-1];   // strict: stable for equal values -> lower index first
          if (sw){
            float tf = tv[r]; tv[r]=tv[r-1]; tv[r-1]=tf;
            int  tii = ti[r]; ti[r]=ti[r-1]; ti[r-1]=tii;
          }
        }
      }
    }
  }

  __syncthreads();
  #pragma unroll
  for(int r=0;r<20;r++){ mv[(sq*4+sl)*20 + r] = tv[r]; mi[(sq*4+sl)*20 + r] = ti[r]; }
  __syncthreads();

  if (t < 32){
    int q = t;
    float hv[4]; int hi[4]; int hp[4];
    #pragma unroll
    for(int l=0;l<4;l++){ hp[l]=0; hv[l]=mv[(q*4+l)*20]; hi[l]=mi[(q*4+l)*20]; }
    int* op = idxout + ((long)b*NP + q0 + q)*KK;
    for(int r=0;r<KK;r++){
      float bv = hv[0]; int bi = hi[0]; int wl = 0;
      #pragma unroll
      for(int l=1;l<4;l++){
        bool bt = (hv[l] > bv) || (hv[l]==bv && hi[l] < bi);
        if (bt){ bv=hv[l]; bi=hi[l]; wl=l; }
      }
      op[r] = bi;
      #pragma unroll
      for(int l=0;l<4;l++){
        if (l == wl){
          hp[l]++;
          if (hp[l] < 20){ hv[l] = mv[(q*4+l)*20 + hp[l]]; hi[l] = mi[(q*4+l)*20 + hp[l]]; }
          else { hv[l] = -__builtin_inff(); hi[l] = 0x7FFFFFFF; }
        }
      }
    }
  }
}

// ---------------- edge conv as two small GEMMs: ya = Wa@x, dd = (Wb-Wa)@x, layout (B,N,O) ----------------
template<int CIN, int O>
__global__ __launch_bounds__(256) void pcdual_kernel(const float* __restrict__ x, long ldb,
                                                     const float* __restrict__ W,
                                                     float* __restrict__ ya, float* __restrict__ dd){
  __shared__ float Wt[CIN][O+1];
  constexpr int NLOC = 256/O;
  const int b = blockIdx.y;
  const int n0 = blockIdx.x*NLOC;
  const int t = threadIdx.x;
  const int o = t % O;
  const int n = n0 + t/O;
  const float* xp = x + (long)b*ldb + n;
  float xv[CIN];
  #pragma unroll
  for(int c=0;c<CIN;c++) xv[c] = xp[(long)c*NP];
  for(int i=t;i<CIN*O;i+=256){ int oo=i/CIN, c=i%CIN; Wt[c][oo] = W[(long)oo*2*CIN + c]; }
  __syncthreads();
  float aa = 0.f;
  #pragma unroll
  for(int c=0;c<CIN;c++) aa += Wt[c][o]*xv[c];
  __syncthreads();
  for(int i=t;i<CIN*O;i+=256){ int oo=i/CIN, c=i%CIN; Wt[c][oo] = W[(long)oo*2*CIN + CIN + c]; }
  __syncthreads();
  float ab = 0.f;
  #pragma unroll
  for(int c=0;c<CIN;c++) ab += Wt[c][o]*xv[c];
  long outoff = ((long)b*NP + n)*O + o;
  ya[outoff] = aa;
  dd[outoff] = ab - aa;
}

// ---------------- edge gather: per (b,o,n) max/min over k; per (b,group) sum/sumsq ----------------
template<int O>
__global__ void egather_kernel(const float* __restrict__ ya, const float* __restrict__ dd,
                               const int* __restrict__ idx,
                               float* __restrict__ mx, float* __restrict__ mn,
                               float* __restrict__ stats){
  const int b = blockIdx.y;
  const int n0 = blockIdx.x*8;
  const int o = threadIdx.x;
  constexpr int CPG = O/8;
  float gs = 0.f, gs2 = 0.f;
  const float* yab = ya + (long)b*NP*O;
  for(int p=0;p<8;p++){
    int n = n0 + p;
    float d = dd[((long)b*NP + n)*O + o];
    const int* ip = idx + ((long)b*NP + n)*KK;
    float m = -__builtin_inff(), mm = __builtin_inff(), s = 0.f, s2 = 0.f;
    #pragma unroll
    for(int k=0;k<KK;k++){
      int j = ip[k];
      float v = yab[(long)j*O + o] + d;
      s += v; s2 += v*v;
      m = fmaxf(m, v); mm = fminf(mm, v);
    }
    mx[((long)b*NP + n)*O + o] = m;
    mn[((long)b*NP + n)*O + o] = mm;
    gs += s; gs2 += s2;
  }
  #pragma unroll
  for(int offm=1; offm<CPG; offm<<=1){
    gs  += __shfl_xor(gs,  offm, CPG);
    gs2 += __shfl_xor(gs2, offm, CPG);
  }
  if ((o & (CPG-1)) == 0){
    int g = o / CPG;
    atomicAdd(&stats[(b*8 + g)*2],   gs);
    atomicAdd(&stats[(b*8 + g)*2+1], gs2);
  }
}

// ---------------- edge normalize (+leaky) with (N,O)->(O,N) transpose into feats ----------------
template<int O>
__global__ __launch_bounds__(256) void enorm_kernel(const float* __restrict__ mx, const float* __restrict__ mn,
                                                    const float* __restrict__ stats,
                                                    const float* __restrict__ gw, const float* __restrict__ gb,
                                                    float* __restrict__ feats, int coff){
  __shared__ float lmx[64][65];
  __shared__ float lmn[64][65];
  const int b = blockIdx.z;
  const int o0 = blockIdx.y*64;
  const int n0 = blockIdx.x*64;
  const int t = threadIdx.x;
  for(int r=0;r<16;r++){
    int i = r*4 + t/64, j = t%64;
    long src = ((long)b*NP + n0 + i)*O + o0 + j;
    lmx[i][j] = mx[src];
    lmn[i][j] = mn[src];
  }
  __syncthreads();
  constexpr int CPG = O/8;
  const float inv_cnt = 1.f/((float)CPG*NP*KK);
  for(int r=0;r<16;r++){
    int ol = r*4 + t/64, nl = t%64;
    int og = o0 + ol;
    int g = og / CPG;
    float S  = stats[(b*8+g)*2];
    float S2 = stats[(b*8+g)*2+1];
    float mu = S*inv_cnt;
    float var = S2*inv_cnt - mu*mu;
    float rs = rsqrtf(var + EPSV);
    float w = gw[og], bb = gb[og];
    float sel = (w >= 0.f) ? lmx[nl][ol] : lmn[nl][ol];
    float v = (sel - mu)*rs*w + bb;
    feats[((long)b*256 + coff + og)*NP + n0 + nl] = leakyf(v);
  }
}

// ---------------- generic tiled GEMM y=W@x (+bias/base) with optional GN stats and per-(b,o) max/min ----------------
template<bool WRITE_Y, bool DO_STATS, bool DO_MAXMIN>
__global__ __launch_bounds__(256) void gemm_kernel(
    const float* __restrict__ W, int ldw,
    const float* __restrict__ x, long xldb,
    const float* __restrict__ bias, const float* __restrict__ base,
    int O, int C, int gch,
    float* __restrict__ y, float* __restrict__ stats,
    unsigned* __restrict__ mmax, unsigned* __restrict__ mmin)
{
  __shared__ float Wl[32][68];
  __shared__ float Xl[32][132];
  __shared__ float sred[8];
  __shared__ unsigned smax[64];
  __shared__ unsigned smin[64];
  const int b  = blockIdx.z;
  const int o0 = blockIdx.y*64;
  const int nb = blockIdx.x*128;
  const int t  = threadIdx.x;
  const int og = t & 15, ng = t >> 4;
  const int ol = og*4,  nl = ng*8;
  if (DO_STATS && t < 8) sred[t] = 0.f;
  if (DO_MAXMIN && t < 64){ smax[t] = 0u; smin[t] = 0xFFFFFFFFu; }
  float acc[4][8];
  #pragma unroll
  for(int i=0;i<4;i++)
    #pragma unroll
    for(int j=0;j<8;j++) acc[i][j]=0.f;

  const int so = t>>2, scs = (t&3)*8;
  const int sc = t>>3, sns = (t&7)*16;

  for(int cc=0; cc<C; cc+=32){
    __syncthreads();
    {
      const float* wp = W + (long)(o0+so)*ldw + cc + scs;
      float4 w0 = *(const float4*)wp;
      float4 w1 = *(const float4*)(wp+4);
      Wl[scs+0][so]=w0.x; Wl[scs+1][so]=w0.y; Wl[scs+2][so]=w0.z; Wl[scs+3][so]=w0.w;
      Wl[scs+4][so]=w1.x; Wl[scs+5][so]=w1.y; Wl[scs+6][so]=w1.z; Wl[scs+7][so]=w1.w;
    }
    {
      const float* xp = x + (long)b*xldb + (long)(cc+sc)*NP + nb + sns;
      *(float4*)&Xl[sc][sns+0]  = *(const float4*)(xp+0);
      *(float4*)&Xl[sc][sns+4]  = *(const float4*)(xp+4);
      *(float4*)&Xl[sc][sns+8]  = *(const float4*)(xp+8);
      *(float4*)&Xl[sc][sns+12] = *(const float4*)(xp+12);
    }
    __syncthreads();
    #pragma unroll
    for(int c=0;c<32;c++){
      float w0=Wl[c][ol+0], w1=Wl[c][ol+1], w2=Wl[c][ol+2], w3=Wl[c][ol+3];
      #pragma unroll
      for(int j=0;j<8;j++){
        float xv = Xl[c][nl+j];
        acc[0][j] += w0*xv;
        acc[1][j] += w1*xv;
        acc[2][j] += w2*xv;
        acc[3][j] += w3*xv;
      }
    }
  }
  float bb[4];
  #pragma unroll
  for(int i=0;i<4;i++){
    float v = 0.f;
    if (bias) v += bias[o0+ol+i];
    if (base) v += base[(long)b*O + o0+ol+i];
    bb[i]=v;
  }
  #pragma unroll
  for(int i=0;i<4;i++)
    #pragma unroll
    for(int j=0;j<8;j++) acc[i][j] += bb[i];

  if (WRITE_Y){
    #pragma unroll
    for(int i=0;i<4;i++){
      float* yp = y + ((long)b*O + o0+ol+i)*NP + nb + nl;
      float4 a0 = {acc[i][0],acc[i][1],acc[i][2],acc[i][3]};
      float4 a1 = {acc[i][4],acc[i][5],acc[i][6],acc[i][7]};
      *(float4*)(yp+0) = a0;
      *(float4*)(yp+4) = a1;
    }
  }
  if (DO_STATS){
    float s=0.f, s2=0.f;
    #pragma unroll
    for(int i=0;i<4;i++)
      #pragma unroll
      for(int j=0;j<8;j++){ float v=acc[i][j]; s+=v; s2+=v*v; }
    int gib = ol / gch;
    atomicAdd(&sred[gib*2],   s);
    atomicAdd(&sred[gib*2+1], s2);
  }
  if (DO_MAXMIN){
    #pragma unroll
    for(int i=0;i<4;i++){
      float mv=acc[i][0], mw=acc[i][0];
      #pragma unroll
      for(int j=1;j<8;j++){ mv=fmaxf(mv,acc[i][j]); mw=fminf(mw,acc[i][j]); }
      atomicMax(&smax[ol+i], fenc(mv));
      atomicMin(&smin[ol+i], fenc(mw));
    }
  }
  if (DO_STATS || DO_MAXMIN) __syncthreads();
  if (DO_STATS){
    int ngb = 64/gch;
    if (t < ngb*2){
      int g = o0/gch + (t>>1);
      atomicAdd(&stats[((long)b*(O/gch) + g)*2 + (t&1)], sred[t]);
    }
  }
  if (DO_MAXMIN){
    if (t < 64){
      atomicMax(&mmax[(long)b*O + o0 + t], smax[t]);
      atomicMin(&mmin[(long)b*O + o0 + t], smin[t]);
    }
  }
}

// ---------------- in-place GN+relu ----------------
__global__ __launch_bounds__(256) void normrelu_kernel(float* __restrict__ y,
    const float* __restrict__ stats, const float* __restrict__ gw, const float* __restrict__ gb,
    int O, int gch, float inv_cnt)
{
  long i4 = (long)blockIdx.x*256 + threadIdx.x;
  long i = i4*4;
  int o = (int)((i/NP) % O);
  int b = (int)(i/((long)O*NP));
  int g = o / gch;
  const float* sp = stats + ((long)b*(O/gch)+g)*2;
  float mu = sp[0]*inv_cnt;
  float var = sp[1]*inv_cnt - mu*mu;
  float rs = rsqrtf(var + EPSV);
  float a = rs*gw[o];
  float c2 = gb[o] - mu*a;
  float4* yp = (float4*)y;
  float4 v = yp[i4];
  v.x = fmaxf(v.x*a + c2, 0.f);
  v.y = fmaxf(v.y*a + c2, 0.f);
  v.z = fmaxf(v.z*a + c2, 0.f);
  v.w = fmaxf(v.w*a + c2, 0.f);
  yp[i4] = v;
}

// ---------------- xmax = relu(gn(max/min over n)) ----------------
__global__ void xmax_kernel(const unsigned* __restrict__ mmax, const unsigned* __restrict__ mmin,
                            const float* __restrict__ stats, const float* __restrict__ gw,
                            const float* __restrict__ gb, float* __restrict__ xmax){
  int t = blockIdx.x*256 + threadIdx.x;
  int b = t >> 10, o = t & 1023;
  int g = o >> 5;
  const float* sp = stats + (b*32+g)*2;
  const float inv_cnt = 1.f/(32.f*NP);
  float mu = sp[0]*inv_cnt;
  float var = sp[1]*inv_cnt - mu*mu;
  float rs = rsqrtf(var + EPSV);
  float w = gw[o];
  float sel = (w >= 0.f) ? fdec(mmax[t]) : fdec(mmin[t]);
  float v = (sel - mu)*rs*w + gb[o];
  xmax[t] = fmaxf(v, 0.f);
}

// ---------------- base1[b,o] = bs1[o] + Ws1[:, :1024] @ xmax[b] ----------------
__global__ void base1_kernel(const float* __restrict__ Ws1, const float* __restrict__ bs1,
                             const float* __restrict__ xmax, float* __restrict__ base1){
  int t = blockIdx.x*256 + threadIdx.x;
  int b = t >> 9, o = t & 511;
  float a = bs1[o];
  const float* wp = Ws1 + (long)o*1280;
  const float* xp = xmax + b*1024;
  for(int c=0;c<1024;c++) a += wp[c]*xp[c];
  base1[t] = a;
}

// ---------------- final 50-class conv + log_softmax ----------------
__global__ __launch_bounds__(256) void s4_kernel(const float* __restrict__ h3,
                                                 const float* __restrict__ W,
                                                 const float* __restrict__ bias,
                                                 float* __restrict__ out){
  int b = blockIdx.y;
  int n = blockIdx.x*256 + threadIdx.x;
  float hv[128];
  #pragma unroll
  for(int c=0;c<128;c++) hv[c] = h3[((long)b*128 + c)*NP + n];
  float m = -__builtin_inff(), ssum = 0.f;
  for(int o=0;o<50;o++){
    float a = bias[o];
    const float* wp = W + o*128;
    #pragma unroll
    for(int c=0;c<128;c++) a += wp[c]*hv[c];
    if (a > m){ ssum = ssum*__expf(m - a) + 1.f; m = a; }
    else      { ssum += __expf(a - m); }
  }
  float lse = m + __logf(ssum);
  for(int o=0;o<50;o++){
    float a = bias[o];
    const float* wp = W + o*128;
    #pragma unroll
    for(int c=0;c<128;c++) a += wp[c]*hv[c];
    out[((long)b*50 + o)*NP + n] = a - lse;
  }
}

extern "C" void kernel_launch(void* const* d_in, const int* in_sizes, int n_in,
                              void* d_out, int out_size, void* d_ws, size_t ws_size,
                              hipStream_t stream)
{
  const float* x   = (const float*)d_in[0];
  const float* W1  = (const float*)d_in[1];
  const float* W2  = (const float*)d_in[2];
  const float* W3  = (const float*)d_in[3];
  const float* g1w = (const float*)d_in[4];
  const float* g1b = (const float*)d_in[5];
  const float* g2w = (const float*)d_in[6];
  const float* g2b = (const float*)d_in[7];
  const float* g3w = (const float*)d_in[8];
  const float* g3b = (const float*)d_in[9];
  const float* gfw = (const float*)d_in[10];
  const float* gfb = (const float*)d_in[11];
  const float* gs1w= (const float*)d_in[12];
  const float* gs1b= (const float*)d_in[13];
  const float* gs2w= (const float*)d_in[14];
  const float* gs2b= (const float*)d_in[15];
  const float* gs3w= (const float*)d_in[16];
  const float* gs3b= (const float*)d_in[17];
  const float* Wm  = (const float*)d_in[18];
  const float* bm  = (const float*)d_in[19];
  const float* Ws1 = (const float*)d_in[20];
  const float* bs1 = (const float*)d_in[21];
  const float* Ws2 = (const float*)d_in[22];
  const float* bs2 = (const float*)d_in[23];
  const float* Ws3 = (const float*)d_in[24];
  const float* bs3 = (const float*)d_in[25];
  const float* Ws4 = (const float*)d_in[26];
  const float* bs4 = (const float*)d_in[27];
  float* out = (float*)d_out;

  char* ws = (char*)d_ws;
  size_t off = 0;
  auto alloc = [&](size_t bytes)->char*{
    char* p = ws + off;
    off += (bytes + 255) & ~(size_t)255;
    return p;
  };
  // zeroed region (stats + mmax), then mmin (0xFF)
  char* zbase = alloc(6656 + 32768);
  float* estats1 = (float*)(zbase + 0);
  float* estats2 = (float*)(zbase + 512);
  float* estats3 = (float*)(zbase + 1024);
  float* mstats  = (float*)(zbase + 1536);   // 8*32*2 floats = 2048 B
  float* s1stats = (float*)(zbase + 3584);   // 8*16*2 = 1024 B
  float* s2stats = (float*)(zbase + 4608);   // 1024 B
  float* s3stats = (float*)(zbase + 5632);   // 512 B
  unsigned* mmax = (unsigned*)(zbase + 6656);
  unsigned* mmin = (unsigned*)alloc(32768);
  float* xmaxb = (float*)alloc(8*1024*4);
  float* base1 = (float*)alloc(8*512*4);
  float* feats = (float*)alloc((size_t)BN*256*NP*4);
  int*   idxb  = (int*)  alloc((size_t)BN*NP*KK*4);
  float* xxb   = (float*)alloc((size_t)BN*NP*4);
  float* ya    = (float*)alloc((size_t)BN*NP*128*4);
  float* dd    = (float*)alloc((size_t)BN*NP*128*4);
  float* mx    = (float*)alloc((size_t)BN*NP*128*4);
  float* mn    = (float*)alloc((size_t)BN*NP*128*4);
  float* ybuf1 = (float*)alloc((size_t)BN*512*NP*4);
  float* ybuf2 = (float*)alloc((size_t)BN*256*NP*4);
  float* ybuf3 = (float*)alloc((size_t)BN*128*NP*4);

  hipMemsetAsync(zbase, 0, 6656 + 32768, stream);
  hipMemsetAsync(mmin, 0xFF, 32768, stream);

  dim3 blk256(256);
  dim3 blk128(128);

  // ---- edge block 1 (C=3 -> 64) ----
  xx_kernel<<<dim3(NP/256, BN), blk256, 0, stream>>>(x, (long)3*NP, 3, xxb);
  knn2_kernel<3><<<dim3(NP/32, BN), blk128, 0, stream>>>(x, (long)3*NP, xxb, idxb);
  pcdual_kernel<3,64><<<dim3(NP/4, BN), blk256, 0, stream>>>(x, (long)3*NP, W1, ya, dd);
  egather_kernel<64><<<dim3(NP/8, BN), dim3(64), 0, stream>>>(ya, dd, idxb, mx, mn, estats1);
  enorm_kernel<64><<<dim3(NP/64, 1, BN), blk256, 0, stream>>>(mx, mn, estats1, g1w, g1b, feats, 0);

  // ---- edge block 2 (C=64 -> 64) ----
  xx_kernel<<<dim3(NP/256, BN), blk256, 0, stream>>>(feats, (long)256*NP, 64, xxb);
  knn2_kernel<64><<<dim3(NP/32, BN), blk128, 0, stream>>>(feats, (long)256*NP, xxb, idxb);
  pcdual_kernel<64,64><<<dim3(NP/4, BN), blk256, 0, stream>>>(feats, (long)256*NP, W2, ya, dd);
  egather_kernel<64><<<dim3(NP/8, BN), dim3(64), 0, stream>>>(ya, dd, idxb, mx, mn, estats2);
  enorm_kernel<64><<<dim3(NP/64, 1, BN), blk256, 0, stream>>>(mx, mn, estats2, g2w, g2b, feats, 64);

  // ---- edge block 3 (C=64 -> 128) ----
  xx_kernel<<<dim3(NP/256, BN), blk256, 0, stream>>>(feats + 64*NP, (long)256*NP, 64, xxb);
  knn2_kernel<64><<<dim3(NP/32, BN), blk128, 0, stream>>>(feats + 64*NP, (long)256*NP, xxb, idxb);
  pcdual_kernel<64,128><<<dim3(NP/2, BN), blk256, 0, stream>>>(feats + 64*NP, (long)256*NP, W3, ya, dd);
  egather_kernel<128><<<dim3(NP/8, BN), dim3(128), 0, stream>>>(ya, dd, idxb, mx, mn, estats3);
  enorm_kernel<128><<<dim3(NP/64, 2, BN), blk256, 0, stream>>>(mx, mn, estats3, g3w, g3b, feats, 128);

  // ---- global conv (Wm 1024x256): stats + per-(b,o) max/min only, no y ----
  gemm_kernel<false,true,true><<<dim3(16,16,BN), blk256, 0, stream>>>(
      Wm, 256, feats, (long)256*NP, bm, nullptr, 1024, 256, 32,
      nullptr, mstats, mmax, mmin);
  xmax_kernel<<<dim3(32), blk256, 0, stream>>>(mmax, mmin, mstats, gfw, gfb, xmaxb);
  base1_kernel<<<dim3(16), blk256, 0, stream>>>(Ws1, bs1, xmaxb, base1);

  // ---- seg conv 1 (feats part of Ws1) ----
  gemm_kernel<true,true,false><<<dim3(16,8,BN), blk256, 0, stream>>>(
      Ws1 + 1024, 1280, feats, (long)256*NP, nullptr, base1, 512, 256, 32,
      ybuf1, s1stats, nullptr, nullptr);
  normrelu_kernel<<<dim3((unsigned)((long)BN*512*NP/4/256)), blk256, 0, stream>>>(
      ybuf1, s1stats, gs1w, gs1b, 512, 32, 1.f/(32.f*NP));

  // ---- seg conv 2 ----
  gemm_kernel<true,true,false><<<dim3(16,4,BN), blk256, 0, stream>>>(
      Ws2, 512, ybuf1, (long)512*NP, bs2, nullptr, 256, 512, 16,
      ybuf2, s2stats, nullptr, nullptr);
  normrelu_kernel<<<dim3((unsigned)((long)BN*256*NP/4/256)), blk256, 0, stream>>>(
      ybuf2, s2stats, gs2w, gs2b, 256, 16, 1.f/(16.f*NP));

  // ---- seg conv 3 ----
  gemm_kernel<true,true,false><<<dim3(16,2,BN), blk256, 0, stream>>>(
      Ws3, 256, ybuf2, (long)256*NP, bs3, nullptr, 128, 256, 16,
      ybuf3, s3stats, nullptr, nullptr);
  normrelu_kernel<<<dim3((unsigned)((long)BN*128*NP/4/256)), blk256, 0, stream>>>(
      ybuf3, s3stats, gs3w, gs3b, 128, 16, 1.f/(16.f*NP));

  // ---- final conv + log_softmax ----
  s4_kernel<<<dim3(NP/256, BN), blk256, 0, stream>>>(ybuf3, Ws4, bs4, out);
}

// Round 3
// 1515.263 us; speedup vs baseline: 45.1190x; 1.1238x over previous
//
#include <hip/hip_runtime.h>

#define BN 8
#define NP 2048
#define KK 20
#define EPSV 1e-5f

static __device__ __forceinline__ float leakyf(float v){ return v >= 0.f ? v : 0.2f*v; }
static __device__ __forceinline__ unsigned fenc(float f){
  unsigned u = __float_as_uint(f);
  return (u & 0x80000000u) ? ~u : (u | 0x80000000u);
}
static __device__ __forceinline__ float fdec(unsigned u){
  return __uint_as_float((u & 0x80000000u) ? (u & 0x7FFFFFFFu) : ~u);
}

// ---------------- xx = sum_c x^2 ----------------
__global__ __launch_bounds__(256) void xx_kernel(const float* __restrict__ x, long ldb, int C,
                                                 float* __restrict__ xx){
  int b = blockIdx.y;
  int n = blockIdx.x*256 + threadIdx.x;
  const float* xp = x + (long)b*ldb + n;
  float a = 0.f;
  for(int c=0;c<C;c++){ float v = xp[(long)c*NP]; a += v*v; }
  xx[b*NP + n] = a;
}

// ---------------- knn v3: 64q x 64c tile, candidate-split parts, partial top-20 lists ----------------
// 256 threads. GEMM map: tq=t>>4 (16), tm=t&15 (16), thread tile 4q x 4m.
// Select map: sq=t>>2 (64 queries), sl=t&3 (4 lanes/query, 16 cands each per chunk).
// Each (part, lane) emits a sorted top-20 list; knnmerge does the 16-way merge.
template<int C, int PARTS>
__global__ __launch_bounds__(256) void knn3_kernel(const float* __restrict__ x, long ldb,
                                                   const float* __restrict__ xx,
                                                   float* __restrict__ pv, int* __restrict__ pi){
  __shared__ float qL[C][64];
  __shared__ float cL[C][64];
  __shared__ float S[64][68];   // 68: float4-aligned rows, conflict-optimal stores+reads
  const int b    = blockIdx.z;
  const int part = blockIdx.y;
  const int q0   = blockIdx.x*64;
  const int t    = threadIdx.x;
  const float* xb  = x + (long)b*ldb;
  const float* xxb = xx + b*NP;

  for(int i=t; i<C*16; i+=256){
    int c = i>>4, q4 = (i&15)*4;
    *(float4*)&qL[c][q4] = *(const float4*)(xb + (long)c*NP + q0 + q4);
  }

  const int tq = t>>4, tm = t&15;
  const int sq = t>>2, sl = t&3;
  float qxx[4];
  #pragma unroll
  for(int i=0;i<4;i++) qxx[i] = xxb[q0 + tq*4 + i];

  float tv[20]; int ti[20];
  #pragma unroll
  for(int r=0;r<20;r++){ tv[r] = -__builtin_inff(); ti[r] = 0x7FFFFFFF; }

  constexpr int CHUNKS = (NP/64)/PARTS;
  for(int cc=0; cc<CHUNKS; cc++){
    const int ct = part*CHUNKS + cc;
    __syncthreads();
    for(int i=t; i<C*16; i+=256){
      int c = i>>4, m4 = (i&15)*4;
      *(float4*)&cL[c][m4] = *(const float4*)(xb + (long)c*NP + ct*64 + m4);
    }
    __syncthreads();
    float acc[4][4];
    #pragma unroll
    for(int i=0;i<4;i++){
      #pragma unroll
      for(int j=0;j<4;j++) acc[i][j]=0.f;
    }
    #pragma unroll
    for(int c=0;c<C;c++){
      float4 qv = *(const float4*)&qL[c][tq*4];
      float4 cv = *(const float4*)&cL[c][tm*4];
      acc[0][0] += qv.x*cv.x; acc[0][1] += qv.x*cv.y; acc[0][2] += qv.x*cv.z; acc[0][3] += qv.x*cv.w;
      acc[1][0] += qv.y*cv.x; acc[1][1] += qv.y*cv.y; acc[1][2] += qv.y*cv.z; acc[1][3] += qv.y*cv.w;
      acc[2][0] += qv.z*cv.x; acc[2][1] += qv.z*cv.y; acc[2][2] += qv.z*cv.z; acc[2][3] += qv.z*cv.w;
      acc[3][0] += qv.w*cv.x; acc[3][1] += qv.w*cv.y; acc[3][2] += qv.w*cv.z; acc[3][3] += qv.w*cv.w;
    }
    float4 cxx = *(const float4*)(xxb + ct*64 + tm*4);
    #pragma unroll
    for(int i=0;i<4;i++){
      float4 sv;
      sv.x = 2.f*acc[i][0] - qxx[i] - cxx.x;
      sv.y = 2.f*acc[i][1] - qxx[i] - cxx.y;
      sv.z = 2.f*acc[i][2] - qxx[i] - cxx.z;
      sv.w = 2.f*acc[i][3] - qxx[i] - cxx.w;
      *(float4*)&S[tq*4+i][tm*4] = sv;
    }
    __syncthreads();
    #pragma unroll
    for(int jj=0;jj<4;jj++){
      float4 sv = *(const float4*)&S[sq][sl*16 + jj*4];
      float v4[4] = {sv.x, sv.y, sv.z, sv.w};
      #pragma unroll
      for(int e=0;e<4;e++){
        float v = v4[e];
        if (v > tv[19]){
          tv[19] = v; ti[19] = ct*64 + sl*16 + jj*4 + e;
          #pragma unroll
          for(int r=19;r>0;r--){
            bool sw = tv[r] > tv[r-1];  // strict: stable -> lower index kept first on ties
            if (sw){
              float tf = tv[r]; tv[r]=tv[r-1]; tv[r-1]=tf;
              int  tii = ti[r]; ti[r]=ti[r-1]; ti[r-1]=tii;
            }
          }
        }
      }
    }
  }
  long base = ((((long)b*NP + q0 + sq)*PARTS + part)*4 + sl)*20;
  #pragma unroll
  for(int r=0;r<20;r++){ pv[base+r] = tv[r]; pi[base+r] = ti[r]; }
}

// ---------------- 16-way merge of partial lists -> final top-20 indices ----------------
template<int NL>
__global__ __launch_bounds__(256) void knnmerge_kernel(const float* __restrict__ pv, const int* __restrict__ pi,
                                                       int* __restrict__ idxout){
  long qg = (long)blockIdx.x*256 + threadIdx.x;   // over B*NP
  const float* vb = pv + qg*NL*20;
  const int*   ib = pi + qg*NL*20;
  float hv[NL]; int hi[NL]; int hp[NL];
  #pragma unroll
  for(int l=0;l<NL;l++){ hp[l]=0; hv[l]=vb[l*20]; hi[l]=ib[l*20]; }
  int* op = idxout + qg*KK;
  for(int r=0;r<KK;r++){
    float bv = hv[0]; int bi = hi[0]; int wl = 0;
    #pragma unroll
    for(int l=1;l<NL;l++){
      bool bt = (hv[l] > bv) || (hv[l]==bv && hi[l] < bi);
      if (bt){ bv=hv[l]; bi=hi[l]; wl=l; }
    }
    op[r] = bi;
    #pragma unroll
    for(int l=0;l<NL;l++){
      if (l == wl){
        hp[l]++;
        if (hp[l] < 20){ hv[l] = vb[l*20 + hp[l]]; hi[l] = ib[l*20 + hp[l]]; }
        else { hv[l] = -__builtin_inff(); hi[l] = 0x7FFFFFFF; }
      }
    }
  }
}

// ---------------- edge conv as two small GEMMs: ya = Wa@x, dd = (Wb-Wa)@x, layout (B,N,O) ----------------
template<int CIN, int O>
__global__ __launch_bounds__(256) void pcdual_kernel(const float* __restrict__ x, long ldb,
                                                     const float* __restrict__ W,
                                                     float* __restrict__ ya, float* __restrict__ dd){
  __shared__ float Wt[CIN][O+1];
  constexpr int NLOC = 256/O;
  const int b = blockIdx.y;
  const int n0 = blockIdx.x*NLOC;
  const int t = threadIdx.x;
  const int o = t % O;
  const int n = n0 + t/O;
  const float* xp = x + (long)b*ldb + n;
  float xv[CIN];
  #pragma unroll
  for(int c=0;c<CIN;c++) xv[c] = xp[(long)c*NP];
  for(int i=t;i<CIN*O;i+=256){ int oo=i/CIN, c=i%CIN; Wt[c][oo] = W[(long)oo*2*CIN + c]; }
  __syncthreads();
  float aa = 0.f;
  #pragma unroll
  for(int c=0;c<CIN;c++) aa += Wt[c][o]*xv[c];
  __syncthreads();
  for(int i=t;i<CIN*O;i+=256){ int oo=i/CIN, c=i%CIN; Wt[c][oo] = W[(long)oo*2*CIN + CIN + c]; }
  __syncthreads();
  float ab = 0.f;
  #pragma unroll
  for(int c=0;c<CIN;c++) ab += Wt[c][o]*xv[c];
  long outoff = ((long)b*NP + n)*O + o;
  ya[outoff] = aa;
  dd[outoff] = ab - aa;
}

// ---------------- edge gather: per (b,o,n) max/min over k; per (b,group) sum/sumsq ----------------
template<int O>
__global__ void egather_kernel(const float* __restrict__ ya, const float* __restrict__ dd,
                               const int* __restrict__ idx,
                               float* __restrict__ mx, float* __restrict__ mn,
                               float* __restrict__ stats){
  const int b = blockIdx.y;
  const int n0 = blockIdx.x*8;
  const int o = threadIdx.x;
  constexpr int CPG = O/8;
  float gs = 0.f, gs2 = 0.f;
  const float* yab = ya + (long)b*NP*O;
  for(int p=0;p<8;p++){
    int n = n0 + p;
    float d = dd[((long)b*NP + n)*O + o];
    const int* ip = idx + ((long)b*NP + n)*KK;
    float m = -__builtin_inff(), mm = __builtin_inff(), s = 0.f, s2 = 0.f;
    #pragma unroll
    for(int k=0;k<KK;k++){
      int j = ip[k];
      float v = yab[(long)j*O + o] + d;
      s += v; s2 += v*v;
      m = fmaxf(m, v); mm = fminf(mm, v);
    }
    mx[((long)b*NP + n)*O + o] = m;
    mn[((long)b*NP + n)*O + o] = mm;
    gs += s; gs2 += s2;
  }
  #pragma unroll
  for(int offm=1; offm<CPG; offm<<=1){
    gs  += __shfl_xor(gs,  offm, CPG);
    gs2 += __shfl_xor(gs2, offm, CPG);
  }
  if ((o & (CPG-1)) == 0){
    int g = o / CPG;
    atomicAdd(&stats[(b*8 + g)*2],   gs);
    atomicAdd(&stats[(b*8 + g)*2+1], gs2);
  }
}

// ---------------- edge normalize (+leaky) with (N,O)->(O,N) transpose into feats ----------------
template<int O>
__global__ __launch_bounds__(256) void enorm_kernel(const float* __restrict__ mx, const float* __restrict__ mn,
                                                    const float* __restrict__ stats,
                                                    const float* __restrict__ gw, const float* __restrict__ gb,
                                                    float* __restrict__ feats, int coff){
  __shared__ float lmx[64][65];
  __shared__ float lmn[64][65];
  const int b = blockIdx.z;
  const int o0 = blockIdx.y*64;
  const int n0 = blockIdx.x*64;
  const int t = threadIdx.x;
  for(int r=0;r<16;r++){
    int i = r*4 + t/64, j = t%64;
    long src = ((long)b*NP + n0 + i)*O + o0 + j;
    lmx[i][j] = mx[src];
    lmn[i][j] = mn[src];
  }
  __syncthreads();
  constexpr int CPG = O/8;
  const float inv_cnt = 1.f/((float)CPG*NP*KK);
  for(int r=0;r<16;r++){
    int ol = r*4 + t/64, nl = t%64;
    int og = o0 + ol;
    int g = og / CPG;
    float S  = stats[(b*8+g)*2];
    float S2 = stats[(b*8+g)*2+1];
    float mu = S*inv_cnt;
    float var = S2*inv_cnt - mu*mu;
    float rs = rsqrtf(var + EPSV);
    float w = gw[og], bb = gb[og];
    float sel = (w >= 0.f) ? lmx[nl][ol] : lmn[nl][ol];
    float v = (sel - mu)*rs*w + bb;
    feats[((long)b*256 + coff + og)*NP + n0 + nl] = leakyf(v);
  }
}

// ---------------- generic tiled GEMM y=W@x (+bias/base) with optional GN stats and per-(b,o) max/min ----------------
template<bool WRITE_Y, bool DO_STATS, bool DO_MAXMIN>
__global__ __launch_bounds__(256) void gemm_kernel(
    const float* __restrict__ W, int ldw,
    const float* __restrict__ x, long xldb,
    const float* __restrict__ bias, const float* __restrict__ base,
    int O, int C, int gch,
    float* __restrict__ y, float* __restrict__ stats,
    unsigned* __restrict__ mmax, unsigned* __restrict__ mmin)
{
  __shared__ float Wl[32][68];
  __shared__ float Xl[32][132];
  __shared__ float sred[8];
  __shared__ unsigned smax[64];
  __shared__ unsigned smin[64];
  const int b  = blockIdx.z;
  const int o0 = blockIdx.y*64;
  const int nb = blockIdx.x*128;
  const int t  = threadIdx.x;
  const int og = t & 15, ng = t >> 4;
  const int ol = og*4,  nl = ng*8;
  if (DO_STATS && t < 8) sred[t] = 0.f;
  if (DO_MAXMIN && t < 64){ smax[t] = 0u; smin[t] = 0xFFFFFFFFu; }
  float acc[4][8];
  #pragma unroll
  for(int i=0;i<4;i++)
    #pragma unroll
    for(int j=0;j<8;j++) acc[i][j]=0.f;

  const int so = t>>2, scs = (t&3)*8;
  const int sc = t>>3, sns = (t&7)*16;

  for(int cc=0; cc<C; cc+=32){
    __syncthreads();
    {
      const float* wp = W + (long)(o0+so)*ldw + cc + scs;
      float4 w0 = *(const float4*)wp;
      float4 w1 = *(const float4*)(wp+4);
      Wl[scs+0][so]=w0.x; Wl[scs+1][so]=w0.y; Wl[scs+2][so]=w0.z; Wl[scs+3][so]=w0.w;
      Wl[scs+4][so]=w1.x; Wl[scs+5][so]=w1.y; Wl[scs+6][so]=w1.z; Wl[scs+7][so]=w1.w;
    }
    {
      const float* xp = x + (long)b*xldb + (long)(cc+sc)*NP + nb + sns;
      *(float4*)&Xl[sc][sns+0]  = *(const float4*)(xp+0);
      *(float4*)&Xl[sc][sns+4]  = *(const float4*)(xp+4);
      *(float4*)&Xl[sc][sns+8]  = *(const float4*)(xp+8);
      *(float4*)&Xl[sc][sns+12] = *(const float4*)(xp+12);
    }
    __syncthreads();
    #pragma unroll
    for(int c=0;c<32;c++){
      float w0=Wl[c][ol+0], w1=Wl[c][ol+1], w2=Wl[c][ol+2], w3=Wl[c][ol+3];
      #pragma unroll
      for(int j=0;j<8;j++){
        float xv = Xl[c][nl+j];
        acc[0][j] += w0*xv;
        acc[1][j] += w1*xv;
        acc[2][j] += w2*xv;
        acc[3][j] += w3*xv;
      }
    }
  }
  float bb[4];
  #pragma unroll
  for(int i=0;i<4;i++){
    float v = 0.f;
    if (bias) v += bias[o0+ol+i];
    if (base) v += base[(long)b*O + o0+ol+i];
    bb[i]=v;
  }
  #pragma unroll
  for(int i=0;i<4;i++)
    #pragma unroll
    for(int j=0;j<8;j++) acc[i][j] += bb[i];

  if (WRITE_Y){
    #pragma unroll
    for(int i=0;i<4;i++){
      float* yp = y + ((long)b*O + o0+ol+i)*NP + nb + nl;
      float4 a0 = {acc[i][0],acc[i][1],acc[i][2],acc[i][3]};
      float4 a1 = {acc[i][4],acc[i][5],acc[i][6],acc[i][7]};
      *(float4*)(yp+0) = a0;
      *(float4*)(yp+4) = a1;
    }
  }
  if (DO_STATS){
    float s=0.f, s2=0.f;
    #pragma unroll
    for(int i=0;i<4;i++)
      #pragma unroll
      for(int j=0;j<8;j++){ float v=acc[i][j]; s+=v; s2+=v*v; }
    int gib = ol / gch;
    atomicAdd(&sred[gib*2],   s);
    atomicAdd(&sred[gib*2+1], s2);
  }
  if (DO_MAXMIN){
    #pragma unroll
    for(int i=0;i<4;i++){
      float mv=acc[i][0], mw=acc[i][0];
      #pragma unroll
      for(int j=1;j<8;j++){ mv=fmaxf(mv,acc[i][j]); mw=fminf(mw,acc[i][j]); }
      atomicMax(&smax[ol+i], fenc(mv));
      atomicMin(&smin[ol+i], fenc(mw));
    }
  }
  if (DO_STATS || DO_MAXMIN) __syncthreads();
  if (DO_STATS){
    int ngb = 64/gch;
    if (t < ngb*2){
      int g = o0/gch + (t>>1);
      atomicAdd(&stats[((long)b*(O/gch) + g)*2 + (t&1)], sred[t]);
    }
  }
  if (DO_MAXMIN){
    if (t < 64){
      atomicMax(&mmax[(long)b*O + o0 + t], smax[t]);
      atomicMin(&mmin[(long)b*O + o0 + t], smin[t]);
    }
  }
}

// ---------------- in-place GN+relu ----------------
__global__ __launch_bounds__(256) void normrelu_kernel(float* __restrict__ y,
    const float* __restrict__ stats, const float* __restrict__ gw, const float* __restrict__ gb,
    int O, int gch, float inv_cnt)
{
  long i4 = (long)blockIdx.x*256 + threadIdx.x;
  long i = i4*4;
  int o = (int)((i/NP) % O);
  int b = (int)(i/((long)O*NP));
  int g = o / gch;
  const float* sp = stats + ((long)b*(O/gch)+g)*2;
  float mu = sp[0]*inv_cnt;
  float var = sp[1]*inv_cnt - mu*mu;
  float rs = rsqrtf(var + EPSV);
  float a = rs*gw[o];
  float c2 = gb[o] - mu*a;
  float4* yp = (float4*)y;
  float4 v = yp[i4];
  v.x = fmaxf(v.x*a + c2, 0.f);
  v.y = fmaxf(v.y*a + c2, 0.f);
  v.z = fmaxf(v.z*a + c2, 0.f);
  v.w = fmaxf(v.w*a + c2, 0.f);
  yp[i4] = v;
}

// ---------------- xmax = relu(gn(max/min over n)) ----------------
__global__ void xmax_kernel(const unsigned* __restrict__ mmax, const unsigned* __restrict__ mmin,
                            const float* __restrict__ stats, const float* __restrict__ gw,
                            const float* __restrict__ gb, float* __restrict__ xmax){
  int t = blockIdx.x*256 + threadIdx.x;
  int b = t >> 10, o = t & 1023;
  int g = o >> 5;
  const float* sp = stats + (b*32+g)*2;
  const float inv_cnt = 1.f/(32.f*NP);
  float mu = sp[0]*inv_cnt;
  float var = sp[1]*inv_cnt - mu*mu;
  float rs = rsqrtf(var + EPSV);
  float w = gw[o];
  float sel = (w >= 0.f) ? fdec(mmax[t]) : fdec(mmin[t]);
  float v = (sel - mu)*rs*w + gb[o];
  xmax[t] = fmaxf(v, 0.f);
}

// ---------------- base1[b,o] = bs1[o] + Ws1[:, :1024] @ xmax[b], one block per o ----------------
__global__ __launch_bounds__(256) void base1_kernel(const float* __restrict__ Ws1, const float* __restrict__ bs1,
                                                    const float* __restrict__ xmax, float* __restrict__ base1){
  __shared__ float sred[4][8];
  const int o = blockIdx.x;
  const int t = threadIdx.x;
  const float* wp = Ws1 + (long)o*1280;
  float acc[8];
  #pragma unroll
  for(int bb=0;bb<8;bb++) acc[bb]=0.f;
  #pragma unroll
  for(int cc=0;cc<4;cc++){
    int c = cc*256 + t;
    float w = wp[c];
    #pragma unroll
    for(int bb=0;bb<8;bb++) acc[bb] += w * xmax[bb*1024 + c];
  }
  #pragma unroll
  for(int bb=0;bb<8;bb++){
    float a = acc[bb];
    a += __shfl_xor(a,1);  a += __shfl_xor(a,2);  a += __shfl_xor(a,4);
    a += __shfl_xor(a,8);  a += __shfl_xor(a,16); a += __shfl_xor(a,32);
    acc[bb]=a;
  }
  if ((t&63)==0){
    #pragma unroll
    for(int bb=0;bb<8;bb++) sred[t>>6][bb]=acc[bb];
  }
  __syncthreads();
  if (t<8){
    float a = sred[0][t]+sred[1][t]+sred[2][t]+sred[3][t] + bs1[o];
    base1[t*512 + o] = a;
  }
}

// ---------------- final 50-class conv + log_softmax: 4 lanes per point ----------------
__global__ __launch_bounds__(256) void s4_kernel(const float* __restrict__ h3,
                                                 const float* __restrict__ W,
                                                 const float* __restrict__ bias,
                                                 float* __restrict__ out){
  const int b = blockIdx.y;
  const int n = blockIdx.x*64 + (threadIdx.x>>2);
  const int cl = threadIdx.x & 3;
  float hv[32];
  #pragma unroll
  for(int c=0;c<32;c++) hv[c] = h3[((long)b*128 + cl*32 + c)*NP + n];
  float zz[50];
  #pragma unroll
  for(int o=0;o<50;o++){
    const float* wp = W + o*128 + cl*32;
    float a = 0.f;
    #pragma unroll
    for(int c=0;c<32;c++) a += wp[c]*hv[c];
    a += __shfl_xor(a,1);
    a += __shfl_xor(a,2);
    zz[o] = a + bias[o];
  }
  float m = zz[0];
  #pragma unroll
  for(int o=1;o<50;o++) m = fmaxf(m, zz[o]);
  float s = 0.f;
  #pragma unroll
  for(int o=0;o<50;o++) s += __expf(zz[o]-m);
  float lse = m + __logf(s);
  #pragma unroll
  for(int o=0;o<50;o++){
    if ((o&3)==cl) out[((long)b*50+o)*NP+n] = zz[o]-lse;
  }
}

extern "C" void kernel_launch(void* const* d_in, const int* in_sizes, int n_in,
                              void* d_out, int out_size, void* d_ws, size_t ws_size,
                              hipStream_t stream)
{
  const float* x   = (const float*)d_in[0];
  const float* W1  = (const float*)d_in[1];
  const float* W2  = (const float*)d_in[2];
  const float* W3  = (const float*)d_in[3];
  const float* g1w = (const float*)d_in[4];
  const float* g1b = (const float*)d_in[5];
  const float* g2w = (const float*)d_in[6];
  const float* g2b = (const float*)d_in[7];
  const float* g3w = (const float*)d_in[8];
  const float* g3b = (const float*)d_in[9];
  const float* gfw = (const float*)d_in[10];
  const float* gfb = (const float*)d_in[11];
  const float* gs1w= (const float*)d_in[12];
  const float* gs1b= (const float*)d_in[13];
  const float* gs2w= (const float*)d_in[14];
  const float* gs2b= (const float*)d_in[15];
  const float* gs3w= (const float*)d_in[16];
  const float* gs3b= (const float*)d_in[17];
  const float* Wm  = (const float*)d_in[18];
  const float* bm  = (const float*)d_in[19];
  const float* Ws1 = (const float*)d_in[20];
  const float* bs1 = (const float*)d_in[21];
  const float* Ws2 = (const float*)d_in[22];
  const float* bs2 = (const float*)d_in[23];
  const float* Ws3 = (const float*)d_in[24];
  const float* bs3 = (const float*)d_in[25];
  const float* Ws4 = (const float*)d_in[26];
  const float* bs4 = (const float*)d_in[27];
  float* out = (float*)d_out;

  char* ws = (char*)d_ws;
  size_t off = 0;
  auto alloc = [&](size_t bytes)->char*{
    char* p = ws + off;
    off += (bytes + 255) & ~(size_t)255;
    return p;
  };
  char* zbase = alloc(6656 + 32768);
  float* estats1 = (float*)(zbase + 0);
  float* estats2 = (float*)(zbase + 512);
  float* estats3 = (float*)(zbase + 1024);
  float* mstats  = (float*)(zbase + 1536);
  float* s1stats = (float*)(zbase + 3584);
  float* s2stats = (float*)(zbase + 4608);
  float* s3stats = (float*)(zbase + 5632);
  unsigned* mmax = (unsigned*)(zbase + 6656);
  unsigned* mmin = (unsigned*)alloc(32768);
  float* xmaxb = (float*)alloc(8*1024*4);
  float* base1 = (float*)alloc(8*512*4);
  float* feats = (float*)alloc((size_t)BN*256*NP*4);
  int*   idxb  = (int*)  alloc((size_t)BN*NP*KK*4);
  float* xxb   = (float*)alloc((size_t)BN*NP*4);
  float* ya    = (float*)alloc((size_t)BN*NP*128*4);
  float* dd    = (float*)alloc((size_t)BN*NP*128*4);
  float* mx    = (float*)alloc((size_t)BN*NP*128*4);
  float* mn    = (float*)alloc((size_t)BN*NP*128*4);
  float* ybuf1 = (float*)alloc((size_t)BN*512*NP*4);
  float* ybuf2 = (float*)alloc((size_t)BN*256*NP*4);
  float* ybuf3 = (float*)alloc((size_t)BN*128*NP*4);

  // knn partial-list scratch aliases (lifetimes disjoint from owners):
  // pv (B*NP*16*20 f32 = 21MB) -> ybuf1 (33.5MB, written only in seg phase)
  // pi (21MB) -> ya..mx region (ya+dd+mx = 25.2MB contiguous; written only after merge)
  float* pv = (float*)ybuf1;
  int*   pi = (int*)ya;

  hipMemsetAsync(zbase, 0, 6656 + 32768, stream);
  hipMemsetAsync(mmin, 0xFF, 32768, stream);

  dim3 blk256(256);

  // ---- edge block 1 (C=3 -> 64) ----
  xx_kernel<<<dim3(NP/256, BN), blk256, 0, stream>>>(x, (long)3*NP, 3, xxb);
  knn3_kernel<3,4><<<dim3(NP/64, 4, BN), blk256, 0, stream>>>(x, (long)3*NP, xxb, pv, pi);
  knnmerge_kernel<16><<<dim3(BN*NP/256), blk256, 0, stream>>>(pv, pi, idxb);
  pcdual_kernel<3,64><<<dim3(NP/4, BN), blk256, 0, stream>>>(x, (long)3*NP, W1, ya, dd);
  egather_kernel<64><<<dim3(NP/8, BN), dim3(64), 0, stream>>>(ya, dd, idxb, mx, mn, estats1);
  enorm_kernel<64><<<dim3(NP/64, 1, BN), blk256, 0, stream>>>(mx, mn, estats1, g1w, g1b, feats, 0);

  // ---- edge block 2 (C=64 -> 64) ----
  xx_kernel<<<dim3(NP/256, BN), blk256, 0, stream>>>(feats, (long)256*NP, 64, xxb);
  knn3_kernel<64,4><<<dim3(NP/64, 4, BN), blk256, 0, stream>>>(feats, (long)256*NP, xxb, pv, pi);
  knnmerge_kernel<16><<<dim3(BN*NP/256), blk256, 0, stream>>>(pv, pi, idxb);
  pcdual_kernel<64,64><<<dim3(NP/4, BN), blk256, 0, stream>>>(feats, (long)256*NP, W2, ya, dd);
  egather_kernel<64><<<dim3(NP/8, BN), dim3(64), 0, stream>>>(ya, dd, idxb, mx, mn, estats2);
  enorm_kernel<64><<<dim3(NP/64, 1, BN), blk256, 0, stream>>>(mx, mn, estats2, g2w, g2b, feats, 64);

  // ---- edge block 3 (C=64 -> 128) ----
  xx_kernel<<<dim3(NP/256, BN), blk256, 0, stream>>>(feats + 64*NP, (long)256*NP, 64, xxb);
  knn3_kernel<64,4><<<dim3(NP/64, 4, BN), blk256, 0, stream>>>(feats + 64*NP, (long)256*NP, xxb, pv, pi);
  knnmerge_kernel<16><<<dim3(BN*NP/256), blk256, 0, stream>>>(pv, pi, idxb);
  pcdual_kernel<64,128><<<dim3(NP/2, BN), blk256, 0, stream>>>(feats + 64*NP, (long)256*NP, W3, ya, dd);
  egather_kernel<128><<<dim3(NP/8, BN), dim3(128), 0, stream>>>(ya, dd, idxb, mx, mn, estats3);
  enorm_kernel<128><<<dim3(NP/64, 2, BN), blk256, 0, stream>>>(mx, mn, estats3, g3w, g3b, feats, 128);

  // ---- global conv (Wm 1024x256): stats + per-(b,o) max/min only, no y ----
  gemm_kernel<false,true,true><<<dim3(16,16,BN), blk256, 0, stream>>>(
      Wm, 256, feats, (long)256*NP, bm, nullptr, 1024, 256, 32,
      nullptr, mstats, mmax, mmin);
  xmax_kernel<<<dim3(32), blk256, 0, stream>>>(mmax, mmin, mstats, gfw, gfb, xmaxb);
  base1_kernel<<<dim3(512), blk256, 0, stream>>>(Ws1, bs1, xmaxb, base1);

  // ---- seg conv 1 (feats part of Ws1) ----
  gemm_kernel<true,true,false><<<dim3(16,8,BN), blk256, 0, stream>>>(
      Ws1 + 1024, 1280, feats, (long)256*NP, nullptr, base1, 512, 256, 32,
      ybuf1, s1stats, nullptr, nullptr);
  normrelu_kernel<<<dim3((unsigned)((long)BN*512*NP/4/256)), blk256, 0, stream>>>(
      ybuf1, s1stats, gs1w, gs1b, 512, 32, 1.f/(32.f*NP));

  // ---- seg conv 2 ----
  gemm_kernel<true,true,false><<<dim3(16,4,BN), blk256, 0, stream>>>(
      Ws2, 512, ybuf1, (long)512*NP, bs2, nullptr, 256, 512, 16,
      ybuf2, s2stats, nullptr, nullptr);
  normrelu_kernel<<<dim3((unsigned)((long)BN*256*NP/4/256)), blk256, 0, stream>>>(
      ybuf2, s2stats, gs2w, gs2b, 256, 16, 1.f/(16.f*NP));

  // ---- seg conv 3 ----
  gemm_kernel<true,true,false><<<dim3(16,2,BN), blk256, 0, stream>>>(
      Ws3, 256, ybuf2, (long)256*NP, bs3, nullptr, 128, 256, 16,
      ybuf3, s3stats, nullptr, nullptr);
  normrelu_kernel<<<dim3((unsigned)((long)BN*128*NP/4/256)), blk256, 0, stream>>>(
      ybuf3, s3stats, gs3w, gs3b, 128, 16, 1.f/(16.f*NP));

  // ---- final conv + log_softmax ----
  s4_kernel<<<dim3(NP/64, BN), blk256, 0, stream>>>(ybuf3, Ws4, bs4, out);
}

// Round 4
// 1112.316 us; speedup vs baseline: 61.4638x; 1.3623x over previous
//
#include <hip/hip_runtime.h>

#define BN 8
#define NP 2048
#define KK 20
#define EPSV 1e-5f

static __device__ __forceinline__ float leakyf(float v){ return v >= 0.f ? v : 0.2f*v; }
static __device__ __forceinline__ unsigned fenc(float f){
  unsigned u = __float_as_uint(f);
  return (u & 0x80000000u) ? ~u : (u | 0x80000000u);
}
static __device__ __forceinline__ float fdec(unsigned u){
  return __uint_as_float((u & 0x80000000u) ? (u & 0x7FFFFFFFu) : ~u);
}

// ---------------- xx = sum_c x^2 ----------------
__global__ __launch_bounds__(256) void xx_kernel(const float* __restrict__ x, long ldb, int C,
                                                 float* __restrict__ xx){
  int b = blockIdx.y;
  int n = blockIdx.x*256 + threadIdx.x;
  const float* xp = x + (long)b*ldb + n;
  float a = 0.f;
  for(int c=0;c<C;c++){ float v = xp[(long)c*NP]; a += v*v; }
  xx[b*NP + n] = a;
}

// ---------------- knn v4: 64q x 64c tile + branch-free med3 shift-insert top-20 ----------------
// 256 threads. GEMM map: tq=t>>4 (16), tm=t&15 (16), thread tile 4q x 4m.
// Select map: sq=t>>2 (64 queries), sl=t&3 (4 lanes/query, 16 cands each per chunk).
// Each (part, lane) emits a sorted top-20 list; knnmerge does the 16-way merge.
template<int C, int PARTS>
__global__ __launch_bounds__(256) void knn3_kernel(const float* __restrict__ x, long ldb,
                                                   const float* __restrict__ xx,
                                                   float* __restrict__ pv, int* __restrict__ pi){
  __shared__ float qL[C][64];
  __shared__ float cL[C][64];
  __shared__ float S[64][68];
  const int b    = blockIdx.z;
  const int part = blockIdx.y;
  const int q0   = blockIdx.x*64;
  const int t    = threadIdx.x;
  const float* xb  = x + (long)b*ldb;
  const float* xxb = xx + b*NP;

  for(int i=t; i<C*16; i+=256){
    int c = i>>4, q4 = (i&15)*4;
    *(float4*)&qL[c][q4] = *(const float4*)(xb + (long)c*NP + q0 + q4);
  }

  const int tq = t>>4, tm = t&15;
  const int sq = t>>2, sl = t&3;
  float qxx[4];
  #pragma unroll
  for(int i=0;i<4;i++) qxx[i] = xxb[q0 + tq*4 + i];

  float tv[20]; int ti[20];
  #pragma unroll
  for(int r=0;r<20;r++){ tv[r] = -__builtin_inff(); ti[r] = 0x7FFFFFFF; }

  constexpr int CHUNKS = (NP/64)/PARTS;
  for(int cc=0; cc<CHUNKS; cc++){
    const int ct = part*CHUNKS + cc;
    __syncthreads();
    for(int i=t; i<C*16; i+=256){
      int c = i>>4, m4 = (i&15)*4;
      *(float4*)&cL[c][m4] = *(const float4*)(xb + (long)c*NP + ct*64 + m4);
    }
    __syncthreads();
    float acc[4][4];
    #pragma unroll
    for(int i=0;i<4;i++){
      #pragma unroll
      for(int j=0;j<4;j++) acc[i][j]=0.f;
    }
    #pragma unroll
    for(int c=0;c<C;c++){
      float4 qv = *(const float4*)&qL[c][tq*4];
      float4 cv = *(const float4*)&cL[c][tm*4];
      acc[0][0] += qv.x*cv.x; acc[0][1] += qv.x*cv.y; acc[0][2] += qv.x*cv.z; acc[0][3] += qv.x*cv.w;
      acc[1][0] += qv.y*cv.x; acc[1][1] += qv.y*cv.y; acc[1][2] += qv.y*cv.z; acc[1][3] += qv.y*cv.w;
      acc[2][0] += qv.z*cv.x; acc[2][1] += qv.z*cv.y; acc[2][2] += qv.z*cv.z; acc[2][3] += qv.z*cv.w;
      acc[3][0] += qv.w*cv.x; acc[3][1] += qv.w*cv.y; acc[3][2] += qv.w*cv.z; acc[3][3] += qv.w*cv.w;
    }
    float4 cxx = *(const float4*)(xxb + ct*64 + tm*4);
    #pragma unroll
    for(int i=0;i<4;i++){
      float4 sv;
      sv.x = 2.f*acc[i][0] - qxx[i] - cxx.x;
      sv.y = 2.f*acc[i][1] - qxx[i] - cxx.y;
      sv.z = 2.f*acc[i][2] - qxx[i] - cxx.z;
      sv.w = 2.f*acc[i][3] - qxx[i] - cxx.w;
      *(float4*)&S[tq*4+i][tm*4] = sv;
    }
    __syncthreads();
    #pragma unroll
    for(int jj=0;jj<4;jj++){
      float4 sv = *(const float4*)&S[sq][sl*16 + jj*4];
      float v4[4] = {sv.x, sv.y, sv.z, sv.w};
      #pragma unroll
      for(int e=0;e<4;e++){
        float v = v4[e];
        int gi = ct*64 + sl*16 + jj*4 + e;
        // branch-free parallel shift-insert (all reads use OLD list values; no serial chain)
        float pold = tv[0]; int iold = ti[0];
        bool cprev = v > pold;
        tv[0] = cprev ? v  : pold;
        ti[0] = cprev ? gi : iold;
        #pragma unroll
        for(int r=1;r<20;r++){
          float cold = tv[r]; int icur = ti[r];
          bool c = v > cold;
          tv[r] = __builtin_amdgcn_fmed3f(v, pold, cold);
          int selidx = cprev ? iold : gi;
          ti[r] = c ? selidx : icur;
          pold = cold; iold = icur; cprev = c;
        }
      }
    }
  }
  long base = ((((long)b*NP + q0 + sq)*PARTS + part)*4 + sl)*20;
  #pragma unroll
  for(int r=0;r<20;r++){ pv[base+r] = tv[r]; pi[base+r] = ti[r]; }
}

// ---------------- 16-way merge of partial lists -> final top-20 indices ----------------
template<int NL>
__global__ __launch_bounds__(256) void knnmerge_kernel(const float* __restrict__ pv, const int* __restrict__ pi,
                                                       int* __restrict__ idxout){
  long qg = (long)blockIdx.x*256 + threadIdx.x;   // over B*NP
  const float* vb = pv + qg*NL*20;
  const int*   ib = pi + qg*NL*20;
  float hv[NL]; int hi[NL]; int hp[NL];
  #pragma unroll
  for(int l=0;l<NL;l++){ hp[l]=0; hv[l]=vb[l*20]; hi[l]=ib[l*20]; }
  int* op = idxout + qg*KK;
  for(int r=0;r<KK;r++){
    float bv = hv[0]; int bi = hi[0]; int wl = 0;
    #pragma unroll
    for(int l=1;l<NL;l++){
      bool bt = (hv[l] > bv) || (hv[l]==bv && hi[l] < bi);
      if (bt){ bv=hv[l]; bi=hi[l]; wl=l; }
    }
    op[r] = bi;
    #pragma unroll
    for(int l=0;l<NL;l++){
      if (l == wl){
        hp[l]++;
        if (hp[l] < 20){ hv[l] = vb[l*20 + hp[l]]; hi[l] = ib[l*20 + hp[l]]; }
        else { hv[l] = -__builtin_inff(); hi[l] = 0x7FFFFFFF; }
      }
    }
  }
}

// ---------------- edge conv as two small GEMMs: ya = Wa@x, dd = (Wb-Wa)@x, layout (B,N,O) ----------------
template<int CIN, int O>
__global__ __launch_bounds__(256) void pcdual_kernel(const float* __restrict__ x, long ldb,
                                                     const float* __restrict__ W,
                                                     float* __restrict__ ya, float* __restrict__ dd){
  __shared__ float Wt[CIN][O+1];
  constexpr int NLOC = 256/O;
  const int b = blockIdx.y;
  const int n0 = blockIdx.x*NLOC;
  const int t = threadIdx.x;
  const int o = t % O;
  const int n = n0 + t/O;
  const float* xp = x + (long)b*ldb + n;
  float xv[CIN];
  #pragma unroll
  for(int c=0;c<CIN;c++) xv[c] = xp[(long)c*NP];
  for(int i=t;i<CIN*O;i+=256){ int oo=i/CIN, c=i%CIN; Wt[c][oo] = W[(long)oo*2*CIN + c]; }
  __syncthreads();
  float aa = 0.f;
  #pragma unroll
  for(int c=0;c<CIN;c++) aa += Wt[c][o]*xv[c];
  __syncthreads();
  for(int i=t;i<CIN*O;i+=256){ int oo=i/CIN, c=i%CIN; Wt[c][oo] = W[(long)oo*2*CIN + CIN + c]; }
  __syncthreads();
  float ab = 0.f;
  #pragma unroll
  for(int c=0;c<CIN;c++) ab += Wt[c][o]*xv[c];
  long outoff = ((long)b*NP + n)*O + o;
  ya[outoff] = aa;
  dd[outoff] = ab - aa;
}

// ---------------- edge gather: per (b,o,n) max/min over k; per (b,group) sum/sumsq ----------------
template<int O>
__global__ void egather_kernel(const float* __restrict__ ya, const float* __restrict__ dd,
                               const int* __restrict__ idx,
                               float* __restrict__ mx, float* __restrict__ mn,
                               float* __restrict__ stats){
  const int b = blockIdx.y;
  const int n0 = blockIdx.x*8;
  const int o = threadIdx.x;
  constexpr int CPG = O/8;
  float gs = 0.f, gs2 = 0.f;
  const float* yab = ya + (long)b*NP*O;
  for(int p=0;p<8;p++){
    int n = n0 + p;
    float d = dd[((long)b*NP + n)*O + o];
    const int* ip = idx + ((long)b*NP + n)*KK;
    float m = -__builtin_inff(), mm = __builtin_inff(), s = 0.f, s2 = 0.f;
    #pragma unroll
    for(int k=0;k<KK;k++){
      int j = ip[k];
      float v = yab[(long)j*O + o] + d;
      s += v; s2 += v*v;
      m = fmaxf(m, v); mm = fminf(mm, v);
    }
    mx[((long)b*NP + n)*O + o] = m;
    mn[((long)b*NP + n)*O + o] = mm;
    gs += s; gs2 += s2;
  }
  #pragma unroll
  for(int offm=1; offm<CPG; offm<<=1){
    gs  += __shfl_xor(gs,  offm, CPG);
    gs2 += __shfl_xor(gs2, offm, CPG);
  }
  if ((o & (CPG-1)) == 0){
    int g = o / CPG;
    atomicAdd(&stats[(b*8 + g)*2],   gs);
    atomicAdd(&stats[(b*8 + g)*2+1], gs2);
  }
}

// ---------------- edge normalize (+leaky) with (N,O)->(O,N) transpose into feats ----------------
template<int O>
__global__ __launch_bounds__(256) void enorm_kernel(const float* __restrict__ mx, const float* __restrict__ mn,
                                                    const float* __restrict__ stats,
                                                    const float* __restrict__ gw, const float* __restrict__ gb,
                                                    float* __restrict__ feats, int coff){
  __shared__ float lmx[64][65];
  __shared__ float lmn[64][65];
  const int b = blockIdx.z;
  const int o0 = blockIdx.y*64;
  const int n0 = blockIdx.x*64;
  const int t = threadIdx.x;
  for(int r=0;r<16;r++){
    int i = r*4 + t/64, j = t%64;
    long src = ((long)b*NP + n0 + i)*O + o0 + j;
    lmx[i][j] = mx[src];
    lmn[i][j] = mn[src];
  }
  __syncthreads();
  constexpr int CPG = O/8;
  const float inv_cnt = 1.f/((float)CPG*NP*KK);
  for(int r=0;r<16;r++){
    int ol = r*4 + t/64, nl = t%64;
    int og = o0 + ol;
    int g = og / CPG;
    float S  = stats[(b*8+g)*2];
    float S2 = stats[(b*8+g)*2+1];
    float mu = S*inv_cnt;
    float var = S2*inv_cnt - mu*mu;
    float rs = rsqrtf(var + EPSV);
    float w = gw[og], bb = gb[og];
    float sel = (w >= 0.f) ? lmx[nl][ol] : lmn[nl][ol];
    float v = (sel - mu)*rs*w + bb;
    feats[((long)b*256 + coff + og)*NP + n0 + nl] = leakyf(v);
  }
}

// ---------------- generic tiled GEMM y=W@x (+bias/base) with optional GN stats and per-(b,o) max/min ----------------
template<bool WRITE_Y, bool DO_STATS, bool DO_MAXMIN>
__global__ __launch_bounds__(256) void gemm_kernel(
    const float* __restrict__ W, int ldw,
    const float* __restrict__ x, long xldb,
    const float* __restrict__ bias, const float* __restrict__ base,
    int O, int C, int gch,
    float* __restrict__ y, float* __restrict__ stats,
    unsigned* __restrict__ mmax, unsigned* __restrict__ mmin)
{
  __shared__ float Wl[32][68];
  __shared__ float Xl[32][132];
  __shared__ float sred[8];
  __shared__ unsigned smax[64];
  __shared__ unsigned smin[64];
  const int b  = blockIdx.z;
  const int o0 = blockIdx.y*64;
  const int nb = blockIdx.x*128;
  const int t  = threadIdx.x;
  const int og = t & 15, ng = t >> 4;
  const int ol = og*4,  nl = ng*8;
  if (DO_STATS && t < 8) sred[t] = 0.f;
  if (DO_MAXMIN && t < 64){ smax[t] = 0u; smin[t] = 0xFFFFFFFFu; }
  float acc[4][8];
  #pragma unroll
  for(int i=0;i<4;i++)
    #pragma unroll
    for(int j=0;j<8;j++) acc[i][j]=0.f;

  const int so = t>>2, scs = (t&3)*8;
  const int sc = t>>3, sns = (t&7)*16;

  for(int cc=0; cc<C; cc+=32){
    __syncthreads();
    {
      const float* wp = W + (long)(o0+so)*ldw + cc + scs;
      float4 w0 = *(const float4*)wp;
      float4 w1 = *(const float4*)(wp+4);
      Wl[scs+0][so]=w0.x; Wl[scs+1][so]=w0.y; Wl[scs+2][so]=w0.z; Wl[scs+3][so]=w0.w;
      Wl[scs+4][so]=w1.x; Wl[scs+5][so]=w1.y; Wl[scs+6][so]=w1.z; Wl[scs+7][so]=w1.w;
    }
    {
      const float* xp = x + (long)b*xldb + (long)(cc+sc)*NP + nb + sns;
      *(float4*)&Xl[sc][sns+0]  = *(const float4*)(xp+0);
      *(float4*)&Xl[sc][sns+4]  = *(const float4*)(xp+4);
      *(float4*)&Xl[sc][sns+8]  = *(const float4*)(xp+8);
      *(float4*)&Xl[sc][sns+12] = *(const float4*)(xp+12);
    }
    __syncthreads();
    #pragma unroll
    for(int c=0;c<32;c++){
      float w0=Wl[c][ol+0], w1=Wl[c][ol+1], w2=Wl[c][ol+2], w3=Wl[c][ol+3];
      #pragma unroll
      for(int j=0;j<8;j++){
        float xv = Xl[c][nl+j];
        acc[0][j] += w0*xv;
        acc[1][j] += w1*xv;
        acc[2][j] += w2*xv;
        acc[3][j] += w3*xv;
      }
    }
  }
  float bb[4];
  #pragma unroll
  for(int i=0;i<4;i++){
    float v = 0.f;
    if (bias) v += bias[o0+ol+i];
    if (base) v += base[(long)b*O + o0+ol+i];
    bb[i]=v;
  }
  #pragma unroll
  for(int i=0;i<4;i++)
    #pragma unroll
    for(int j=0;j<8;j++) acc[i][j] += bb[i];

  if (WRITE_Y){
    #pragma unroll
    for(int i=0;i<4;i++){
      float* yp = y + ((long)b*O + o0+ol+i)*NP + nb + nl;
      float4 a0 = {acc[i][0],acc[i][1],acc[i][2],acc[i][3]};
      float4 a1 = {acc[i][4],acc[i][5],acc[i][6],acc[i][7]};
      *(float4*)(yp+0) = a0;
      *(float4*)(yp+4) = a1;
    }
  }
  if (DO_STATS){
    float s=0.f, s2=0.f;
    #pragma unroll
    for(int i=0;i<4;i++)
      #pragma unroll
      for(int j=0;j<8;j++){ float v=acc[i][j]; s+=v; s2+=v*v; }
    int gib = ol / gch;
    atomicAdd(&sred[gib*2],   s);
    atomicAdd(&sred[gib*2+1], s2);
  }
  if (DO_MAXMIN){
    #pragma unroll
    for(int i=0;i<4;i++){
      float mv=acc[i][0], mw=acc[i][0];
      #pragma unroll
      for(int j=1;j<8;j++){ mv=fmaxf(mv,acc[i][j]); mw=fminf(mw,acc[i][j]); }
      atomicMax(&smax[ol+i], fenc(mv));
      atomicMin(&smin[ol+i], fenc(mw));
    }
  }
  if (DO_STATS || DO_MAXMIN) __syncthreads();
  if (DO_STATS){
    int ngb = 64/gch;
    if (t < ngb*2){
      int g = o0/gch + (t>>1);
      atomicAdd(&stats[((long)b*(O/gch) + g)*2 + (t&1)], sred[t]);
    }
  }
  if (DO_MAXMIN){
    if (t < 64){
      atomicMax(&mmax[(long)b*O + o0 + t], smax[t]);
      atomicMin(&mmin[(long)b*O + o0 + t], smin[t]);
    }
  }
}

// ---------------- in-place GN+relu ----------------
__global__ __launch_bounds__(256) void normrelu_kernel(float* __restrict__ y,
    const float* __restrict__ stats, const float* __restrict__ gw, const float* __restrict__ gb,
    int O, int gch, float inv_cnt)
{
  long i4 = (long)blockIdx.x*256 + threadIdx.x;
  long i = i4*4;
  int o = (int)((i/NP) % O);
  int b = (int)(i/((long)O*NP));
  int g = o / gch;
  const float* sp = stats + ((long)b*(O/gch)+g)*2;
  float mu = sp[0]*inv_cnt;
  float var = sp[1]*inv_cnt - mu*mu;
  float rs = rsqrtf(var + EPSV);
  float a = rs*gw[o];
  float c2 = gb[o] - mu*a;
  float4* yp = (float4*)y;
  float4 v = yp[i4];
  v.x = fmaxf(v.x*a + c2, 0.f);
  v.y = fmaxf(v.y*a + c2, 0.f);
  v.z = fmaxf(v.z*a + c2, 0.f);
  v.w = fmaxf(v.w*a + c2, 0.f);
  yp[i4] = v;
}

// ---------------- xmax = relu(gn(max/min over n)) ----------------
__global__ void xmax_kernel(const unsigned* __restrict__ mmax, const unsigned* __restrict__ mmin,
                            const float* __restrict__ stats, const float* __restrict__ gw,
                            const float* __restrict__ gb, float* __restrict__ xmax){
  int t = blockIdx.x*256 + threadIdx.x;
  int b = t >> 10, o = t & 1023;
  int g = o >> 5;
  const float* sp = stats + (b*32+g)*2;
  const float inv_cnt = 1.f/(32.f*NP);
  float mu = sp[0]*inv_cnt;
  float var = sp[1]*inv_cnt - mu*mu;
  float rs = rsqrtf(var + EPSV);
  float w = gw[o];
  float sel = (w >= 0.f) ? fdec(mmax[t]) : fdec(mmin[t]);
  float v = (sel - mu)*rs*w + gb[o];
  xmax[t] = fmaxf(v, 0.f);
}

// ---------------- base1[b,o] = bs1[o] + Ws1[:, :1024] @ xmax[b], one block per o ----------------
__global__ __launch_bounds__(256) void base1_kernel(const float* __restrict__ Ws1, const float* __restrict__ bs1,
                                                    const float* __restrict__ xmax, float* __restrict__ base1){
  __shared__ float sred[4][8];
  const int o = blockIdx.x;
  const int t = threadIdx.x;
  const float* wp = Ws1 + (long)o*1280;
  float acc[8];
  #pragma unroll
  for(int bb=0;bb<8;bb++) acc[bb]=0.f;
  #pragma unroll
  for(int cc=0;cc<4;cc++){
    int c = cc*256 + t;
    float w = wp[c];
    #pragma unroll
    for(int bb=0;bb<8;bb++) acc[bb] += w * xmax[bb*1024 + c];
  }
  #pragma unroll
  for(int bb=0;bb<8;bb++){
    float a = acc[bb];
    a += __shfl_xor(a,1);  a += __shfl_xor(a,2);  a += __shfl_xor(a,4);
    a += __shfl_xor(a,8);  a += __shfl_xor(a,16); a += __shfl_xor(a,32);
    acc[bb]=a;
  }
  if ((t&63)==0){
    #pragma unroll
    for(int bb=0;bb<8;bb++) sred[t>>6][bb]=acc[bb];
  }
  __syncthreads();
  if (t<8){
    float a = sred[0][t]+sred[1][t]+sred[2][t]+sred[3][t] + bs1[o];
    base1[t*512 + o] = a;
  }
}

// ---------------- final 50-class conv + log_softmax: 4 lanes per point ----------------
__global__ __launch_bounds__(256) void s4_kernel(const float* __restrict__ h3,
                                                 const float* __restrict__ W,
                                                 const float* __restrict__ bias,
                                                 float* __restrict__ out){
  const int b = blockIdx.y;
  const int n = blockIdx.x*64 + (threadIdx.x>>2);
  const int cl = threadIdx.x & 3;
  float hv[32];
  #pragma unroll
  for(int c=0;c<32;c++) hv[c] = h3[((long)b*128 + cl*32 + c)*NP + n];
  float zz[50];
  #pragma unroll
  for(int o=0;o<50;o++){
    const float* wp = W + o*128 + cl*32;
    float a = 0.f;
    #pragma unroll
    for(int c=0;c<32;c++) a += wp[c]*hv[c];
    a += __shfl_xor(a,1);
    a += __shfl_xor(a,2);
    zz[o] = a + bias[o];
  }
  float m = zz[0];
  #pragma unroll
  for(int o=1;o<50;o++) m = fmaxf(m, zz[o]);
  float s = 0.f;
  #pragma unroll
  for(int o=0;o<50;o++) s += __expf(zz[o]-m);
  float lse = m + __logf(s);
  #pragma unroll
  for(int o=0;o<50;o++){
    if ((o&3)==cl) out[((long)b*50+o)*NP+n] = zz[o]-lse;
  }
}

extern "C" void kernel_launch(void* const* d_in, const int* in_sizes, int n_in,
                              void* d_out, int out_size, void* d_ws, size_t ws_size,
                              hipStream_t stream)
{
  const float* x   = (const float*)d_in[0];
  const float* W1  = (const float*)d_in[1];
  const float* W2  = (const float*)d_in[2];
  const float* W3  = (const float*)d_in[3];
  const float* g1w = (const float*)d_in[4];
  const float* g1b = (const float*)d_in[5];
  const float* g2w = (const float*)d_in[6];
  const float* g2b = (const float*)d_in[7];
  const float* g3w = (const float*)d_in[8];
  const float* g3b = (const float*)d_in[9];
  const float* gfw = (const float*)d_in[10];
  const float* gfb = (const float*)d_in[11];
  const float* gs1w= (const float*)d_in[12];
  const float* gs1b= (const float*)d_in[13];
  const float* gs2w= (const float*)d_in[14];
  const float* gs2b= (const float*)d_in[15];
  const float* gs3w= (const float*)d_in[16];
  const float* gs3b= (const float*)d_in[17];
  const float* Wm  = (const float*)d_in[18];
  const float* bm  = (const float*)d_in[19];
  const float* Ws1 = (const float*)d_in[20];
  const float* bs1 = (const float*)d_in[21];
  const float* Ws2 = (const float*)d_in[22];
  const float* bs2 = (const float*)d_in[23];
  const float* Ws3 = (const float*)d_in[24];
  const float* bs3 = (const float*)d_in[25];
  const float* Ws4 = (const float*)d_in[26];
  const float* bs4 = (const float*)d_in[27];
  float* out = (float*)d_out;

  char* ws = (char*)d_ws;
  size_t off = 0;
  auto alloc = [&](size_t bytes)->char*{
    char* p = ws + off;
    off += (bytes + 255) & ~(size_t)255;
    return p;
  };
  char* zbase = alloc(6656 + 32768);
  float* estats1 = (float*)(zbase + 0);
  float* estats2 = (float*)(zbase + 512);
  float* estats3 = (float*)(zbase + 1024);
  float* mstats  = (float*)(zbase + 1536);
  float* s1stats = (float*)(zbase + 3584);
  float* s2stats = (float*)(zbase + 4608);
  float* s3stats = (float*)(zbase + 5632);
  unsigned* mmax = (unsigned*)(zbase + 6656);
  unsigned* mmin = (unsigned*)alloc(32768);
  float* xmaxb = (float*)alloc(8*1024*4);
  float* base1 = (float*)alloc(8*512*4);
  float* feats = (float*)alloc((size_t)BN*256*NP*4);
  int*   idxb  = (int*)  alloc((size_t)BN*NP*KK*4);
  float* xxb   = (float*)alloc((size_t)BN*NP*4);
  float* ya    = (float*)alloc((size_t)BN*NP*128*4);
  float* dd    = (float*)alloc((size_t)BN*NP*128*4);
  float* mx    = (float*)alloc((size_t)BN*NP*128*4);
  float* mn    = (float*)alloc((size_t)BN*NP*128*4);
  float* ybuf1 = (float*)alloc((size_t)BN*512*NP*4);
  float* ybuf2 = (float*)alloc((size_t)BN*256*NP*4);
  float* ybuf3 = (float*)alloc((size_t)BN*128*NP*4);

  // knn partial-list scratch aliases (lifetimes disjoint from owners):
  // pv (B*NP*16*20 f32 = 21MB) -> ybuf1 (33.5MB, written only in seg phase)
  // pi (21MB) -> ya..mx region (ya+dd = 32MB contiguous; overwritten only after merge)
  float* pv = (float*)ybuf1;
  int*   pi = (int*)ya;

  hipMemsetAsync(zbase, 0, 6656 + 32768, stream);
  hipMemsetAsync(mmin, 0xFF, 32768, stream);

  dim3 blk256(256);

  // ---- edge block 1 (C=3 -> 64) ----
  xx_kernel<<<dim3(NP/256, BN), blk256, 0, stream>>>(x, (long)3*NP, 3, xxb);
  knn3_kernel<3,4><<<dim3(NP/64, 4, BN), blk256, 0, stream>>>(x, (long)3*NP, xxb, pv, pi);
  knnmerge_kernel<16><<<dim3(BN*NP/256), blk256, 0, stream>>>(pv, pi, idxb);
  pcdual_kernel<3,64><<<dim3(NP/4, BN), blk256, 0, stream>>>(x, (long)3*NP, W1, ya, dd);
  egather_kernel<64><<<dim3(NP/8, BN), dim3(64), 0, stream>>>(ya, dd, idxb, mx, mn, estats1);
  enorm_kernel<64><<<dim3(NP/64, 1, BN), blk256, 0, stream>>>(mx, mn, estats1, g1w, g1b, feats, 0);

  // ---- edge block 2 (C=64 -> 64) ----
  xx_kernel<<<dim3(NP/256, BN), blk256, 0, stream>>>(feats, (long)256*NP, 64, xxb);
  knn3_kernel<64,4><<<dim3(NP/64, 4, BN), blk256, 0, stream>>>(feats, (long)256*NP, xxb, pv, pi);
  knnmerge_kernel<16><<<dim3(BN*NP/256), blk256, 0, stream>>>(pv, pi, idxb);
  pcdual_kernel<64,64><<<dim3(NP/4, BN), blk256, 0, stream>>>(feats, (long)256*NP, W2, ya, dd);
  egather_kernel<64><<<dim3(NP/8, BN), dim3(64), 0, stream>>>(ya, dd, idxb, mx, mn, estats2);
  enorm_kernel<64><<<dim3(NP/64, 1, BN), blk256, 0, stream>>>(mx, mn, estats2, g2w, g2b, feats, 64);

  // ---- edge block 3 (C=64 -> 128) ----
  xx_kernel<<<dim3(NP/256, BN), blk256, 0, stream>>>(feats + 64*NP, (long)256*NP, 64, xxb);
  knn3_kernel<64,4><<<dim3(NP/64, 4, BN), blk256, 0, stream>>>(feats + 64*NP, (long)256*NP, xxb, pv, pi);
  knnmerge_kernel<16><<<dim3(BN*NP/256), blk256, 0, stream>>>(pv, pi, idxb);
  pcdual_kernel<64,128><<<dim3(NP/2, BN), blk256, 0, stream>>>(feats + 64*NP, (long)256*NP, W3, ya, dd);
  egather_kernel<128><<<dim3(NP/8, BN), dim3(128), 0, stream>>>(ya, dd, idxb, mx, mn, estats3);
  enorm_kernel<128><<<dim3(NP/64, 2, BN), blk256, 0, stream>>>(mx, mn, estats3, g3w, g3b, feats, 128);

  // ---- global conv (Wm 1024x256): stats + per-(b,o) max/min only, no y ----
  gemm_kernel<false,true,true><<<dim3(16,16,BN), blk256, 0, stream>>>(
      Wm, 256, feats, (long)256*NP, bm, nullptr, 1024, 256, 32,
      nullptr, mstats, mmax, mmin);
  xmax_kernel<<<dim3(32), blk256, 0, stream>>>(mmax, mmin, mstats, gfw, gfb, xmaxb);
  base1_kernel<<<dim3(512), blk256, 0, stream>>>(Ws1, bs1, xmaxb, base1);

  // ---- seg conv 1 (feats part of Ws1) ----
  gemm_kernel<true,true,false><<<dim3(16,8,BN), blk256, 0, stream>>>(
      Ws1 + 1024, 1280, feats, (long)256*NP, nullptr, base1, 512, 256, 32,
      ybuf1, s1stats, nullptr, nullptr);
  normrelu_kernel<<<dim3((unsigned)((long)BN*512*NP/4/256)), blk256, 0, stream>>>(
      ybuf1, s1stats, gs1w, gs1b, 512, 32, 1.f/(32.f*NP));

  // ---- seg conv 2 ----
  gemm_kernel<true,true,false><<<dim3(16,4,BN), blk256, 0, stream>>>(
      Ws2, 512, ybuf1, (long)512*NP, bs2, nullptr, 256, 512, 16,
      ybuf2, s2stats, nullptr, nullptr);
  normrelu_kernel<<<dim3((unsigned)((long)BN*256*NP/4/256)), blk256, 0, stream>>>(
      ybuf2, s2stats, gs2w, gs2b, 256, 16, 1.f/(16.f*NP));

  // ---- seg conv 3 ----
  gemm_kernel<true,true,false><<<dim3(16,2,BN), blk256, 0, stream>>>(
      Ws3, 256, ybuf2, (long)256*NP, bs3, nullptr, 128, 256, 16,
      ybuf3, s3stats, nullptr, nullptr);
  normrelu_kernel<<<dim3((unsigned)((long)BN*128*NP/4/256)), blk256, 0, stream>>>(
      ybuf3, s3stats, gs3w, gs3b, 128, 16, 1.f/(16.f*NP));

  // ---- final conv + log_softmax ----
  s4_kernel<<<dim3(NP/64, BN), blk256, 0, stream>>>(ybuf3, Ws4, bs4, out);
}